// Round 10
// baseline (214.178 us; speedup 1.0000x reference)
//
#include <hip/hip_runtime.h>
#include <math.h>

// Problem constants
#define BATCH 8
#define DIMD  512
#define NTOK  1024      // H*W
#define NH    8
#define CQKV  640       // 64 K + 64 V + 512 Q
#define DOUT  512

typedef __attribute__((ext_vector_type(8))) short short8;   // MFMA A/B frag (8 bf16)
typedef __attribute__((ext_vector_type(4))) short short4v;
typedef __attribute__((ext_vector_type(4))) float f32x4;    // MFMA C/D frag

__device__ __forceinline__ short bf16rn(float x) {
    unsigned u = __float_as_uint(x);
    u += 0x7FFF + ((u >> 16) & 1);
    return (short)(u >> 16);
}
__device__ __forceinline__ short bf16tr(float x) {          // truncate (P only)
    return (short)(__float_as_uint(x) >> 16);
}
__device__ __forceinline__ float bf16tof(short s) {
    return __uint_as_float(((unsigned)(unsigned short)s) << 16);
}
struct HL { short h, l; };
__device__ __forceinline__ HL bf16split(float x) {
    HL r;
    r.h = bf16rn(x);
    r.l = bf16rn(x - bf16tof(r.h));
    return r;
}
// async global->LDS, 16B/lane; LDS dest = wave-uniform base + lane*16
__device__ __forceinline__ void dma16(const short* g, short* l) {
    __builtin_amdgcn_global_load_lds(
        (const __attribute__((address_space(1))) unsigned int*)g,
        (__attribute__((address_space(3))) unsigned int*)l, 16, 0, 0);
}

// Fragment-order conventions (verified end-to-end R2/R4-R9):
//  A-frag: lane=(q=lane>>4, r=lane&15), element A[m=r][k=q*8+j] per 32-k chunk
//  B-frag: element B[ncol=r][k=q*8+j]
//  C/D   : D[m=q*4+reg][ncol=r]
// K/V global frag buffers: [b][t16][ic8][lane64][j8] = 512 shorts/chunk
// Q global frag buffer:    [b][h][nt64][kc2][lane64][j8]

// ---------------------------------------------------------------------------
// prepack_w: Wcat[d][c] -> B-frag hi/lo  Whi/Wlo[ct40][kt16][lane][8]
// ---------------------------------------------------------------------------
__global__ void prepack_w(const float* __restrict__ qp, const float* __restrict__ kp,
                          const float* __restrict__ vp,
                          short* __restrict__ whi, short* __restrict__ wlo) {
    int tid = blockIdx.x * 256 + threadIdx.x;           // 40960
    int lane = tid & 63, kt = (tid >> 6) & 15, ct = tid >> 10;
    int q = lane >> 4, r = lane & 15;
    int c = ct * 16 + r;
    short8 h, l;
    #pragma unroll
    for (int j = 0; j < 8; ++j) {
        int d = kt * 32 + q * 8 + j;
        float v;
        if (c < 64)       v = kp[d * 64 + c];
        else if (c < 128) v = vp[d * 64 + (c - 64)];
        else              v = qp[(size_t)(c - 128) * DIMD + d];
        HL s = bf16split(v);
        h[j] = s.h; l[j] = s.l;
    }
    *(short8*)&whi[(size_t)tid * 8] = h;
    *(short8*)&wlo[(size_t)tid * 8] = l;
}

// ---------------------------------------------------------------------------
// prepack_x (rewritten): coalesced LDS-transpose.
// Block handles a 64d x 64n tile of x[b]: reads full 256B row-segments
// (float4/lane, 4 rows per wave instruction), transposes through padded LDS,
// emits frag-order short8 (layout identical to R9).
// Grid (16 n-tiles, 8 d-tiles, 8 b) x 256 thr.
// ---------------------------------------------------------------------------
__global__ __launch_bounds__(256) void prepack_x(const float* __restrict__ x,
                                                 short* __restrict__ xhi,
                                                 short* __restrict__ xlo) {
    __shared__ float Cs[64][65];
    const int b = blockIdx.z, dt = blockIdx.y, nt = blockIdx.x;
    const int t = threadIdx.x;
    // load 64x64 tile coalesced
    #pragma unroll
    for (int i = 0; i < 4; ++i) {
        int row = (t >> 4) + i * 16;
        float4 v = *(const float4*)(x + ((size_t)(b * DIMD + dt * 64 + row)) * NTOK
                                      + nt * 64 + (t & 15) * 4);
        Cs[row][(t & 15) * 4 + 0] = v.x;
        Cs[row][(t & 15) * 4 + 1] = v.y;
        Cs[row][(t & 15) * 4 + 2] = v.z;
        Cs[row][(t & 15) * 4 + 3] = v.w;
    }
    __syncthreads();
    // emit frags: chunks (kt_loc 2) x (mt_loc 4), 64 lanes each
    for (int u = t; u < 512; u += 256) {
        int lane2 = u & 63, cidx = u >> 6;
        int q2 = lane2 >> 4, r2 = lane2 & 15;
        int kt_loc = cidx & 1, mt_loc = cidx >> 1;
        short8 h8, l8;
        #pragma unroll
        for (int j = 0; j < 8; ++j) {
            HL s = bf16split(Cs[kt_loc * 32 + q2 * 8 + j][mt_loc * 16 + r2]);
            h8[j] = s.h; l8[j] = s.l;
        }
        size_t off = (((size_t)(b * 64 + nt * 4 + mt_loc)) * 16 + dt * 2 + kt_loc) * 512
                     + lane2 * 8;
        *(short8*)&xhi[off] = h8;
        *(short8*)&xlo[off] = l8;
    }
}

// ---------------------------------------------------------------------------
// qkv_gemm: split-bf16 MFMA + FUSED frag emission (unchanged from R9).
// BM=64(n) BN=64(c) BK=64(d), 4 waves, grid (10,16,8)=1280 blocks.
// ---------------------------------------------------------------------------
__global__ __launch_bounds__(256) void qkv_gemm(const short* __restrict__ xhi,
                                                const short* __restrict__ xlo,
                                                const short* __restrict__ whi,
                                                const short* __restrict__ wlo,
                                                short* __restrict__ khi,
                                                short* __restrict__ klo,
                                                short* __restrict__ vf,
                                                short* __restrict__ qhi,
                                                short* __restrict__ qlo) {
    __shared__ __align__(16) char pool[32768];
    short* Ah = (short*)pool;           // 4096 shorts
    short* Al = Ah + 4096;
    short* Bh = Al + 4096;
    short* Bl = Bh + 4096;
    float (*Cs)[65] = (float(*)[65])pool;   // aliases staging after last use

    const int b = blockIdx.z, bm = blockIdx.y, cb = blockIdx.x;
    const int tid = threadIdx.x, w = tid >> 6, lane = tid & 63;
    const int q = lane >> 4, r = lane & 15;
    f32x4 acc[4];
    #pragma unroll
    for (int j = 0; j < 4; ++j) acc[j] = (f32x4){0.f, 0.f, 0.f, 0.f};

    for (int it = 0; it < 8; ++it) {
        __syncthreads();
        for (int u = w; u < 8; u += 4) {
            size_t ga = ((size_t)((b * 64 + bm * 4 + (u >> 1)) * 16 + it * 2 + (u & 1))) * 512 + lane * 8;
            dma16(xhi + ga, &Ah[u * 512]);
            dma16(xlo + ga, &Al[u * 512]);
            size_t gb = ((size_t)((cb * 4 + (u >> 1)) * 16 + it * 2 + (u & 1))) * 512 + lane * 8;
            dma16(whi + gb, &Bh[u * 512]);
            dma16(wlo + gb, &Bl[u * 512]);
        }
        __syncthreads();
        #pragma unroll
        for (int kc = 0; kc < 2; ++kc) {
            short8 ah = *(short8*)&Ah[(w * 2 + kc) * 512 + lane * 8];
            short8 al = *(short8*)&Al[(w * 2 + kc) * 512 + lane * 8];
            #pragma unroll
            for (int tt = 0; tt < 4; ++tt) {
                short8 bh = *(short8*)&Bh[(tt * 2 + kc) * 512 + lane * 8];
                short8 bl = *(short8*)&Bl[(tt * 2 + kc) * 512 + lane * 8];
                acc[tt] = __builtin_amdgcn_mfma_f32_16x16x32_bf16(ah, bh, acc[tt], 0, 0, 0);
                acc[tt] = __builtin_amdgcn_mfma_f32_16x16x32_bf16(ah, bl, acc[tt], 0, 0, 0);
                acc[tt] = __builtin_amdgcn_mfma_f32_16x16x32_bf16(al, bh, acc[tt], 0, 0, 0);
            }
        }
    }

    // ---- fused epilogue: C tile -> LDS -> frag-order bf16 global ----
    __syncthreads();
    #pragma unroll
    for (int reg = 0; reg < 4; ++reg)
        #pragma unroll
        for (int tt = 0; tt < 4; ++tt)
            Cs[w * 16 + q * 4 + reg][tt * 16 + r] = acc[tt][reg];
    __syncthreads();

    if (cb == 0) {
        for (int u = tid; u < 512; u += 256) {
            int lane2 = u & 63, ic = u >> 6;
            int q2 = lane2 >> 4, r2 = lane2 & 15;
            int i = ic >> 1, cc = ic & 1;
            short8 h8, l8;
            #pragma unroll
            for (int j = 0; j < 8; ++j) {
                HL s = bf16split(Cs[i * 16 + r2][cc * 32 + q2 * 8 + j]);
                h8[j] = s.h; l8[j] = s.l;
            }
            size_t off = ((size_t)(b * 16 + bm) * 8 + ic) * 512 + lane2 * 8;
            *(short8*)&khi[off] = h8;
            *(short8*)&klo[off] = l8;
        }
    } else if (cb == 1) {
        for (int u = tid; u < 512; u += 256) {
            int lane2 = u & 63, ic = u >> 6;
            int q2 = lane2 >> 4, r2 = lane2 & 15;
            int tv = ic >> 1, cc = ic & 1;
            short8 v8;
            #pragma unroll
            for (int j = 0; j < 8; ++j)
                v8[j] = bf16rn(Cs[cc * 32 + q2 * 8 + j][tv * 16 + r2]);
            size_t off = ((size_t)(b * 16 + bm) * 8 + ic) * 512 + lane2 * 8;
            *(short8*)&vf[off] = v8;
        }
    } else {
        const int hd = cb - 2;
        const float qscale = 0.125f * 1.44269504f;
        for (int u = tid; u < 512; u += 256) {
            int lane2 = u & 63, ic = u >> 6;
            int q2 = lane2 >> 4, r2 = lane2 & 15;
            int ntl = ic >> 1, kc = ic & 1;
            short8 h8, l8;
            #pragma unroll
            for (int j = 0; j < 8; ++j) {
                HL s = bf16split(Cs[ntl * 16 + r2][kc * 32 + q2 * 8 + j] * qscale);
                h8[j] = s.h; l8[j] = s.l;
            }
            size_t off = ((((size_t)(b * 8 + hd) * 64 + bm * 4 + ntl) * 2 + kc) * 64 + lane2) * 8;
            *(short8*)&qhi[off] = h8;
            *(short8*)&qlo[off] = l8;
        }
    }
}

// ---------------------------------------------------------------------------
// prepack_wout: out_proj fp32 -> A-frag bf16  Wof[mt32][kt16][lane][8]
// ---------------------------------------------------------------------------
__global__ void prepack_wout(const float* __restrict__ wout, short* __restrict__ wof) {
    int tid = blockIdx.x * 256 + threadIdx.x;           // 32768
    int lane = tid & 63, kt = (tid >> 6) & 15, mt = tid >> 10;
    int q = lane >> 4, r = lane & 15;
    const float* src = wout + (size_t)(mt * 16 + r) * DOUT + kt * 32 + q * 8;
    short8 h;
    #pragma unroll
    for (int j = 0; j < 8; ++j) h[j] = bf16rn(src[j]);
    *(short8*)&wof[(size_t)tid * 8] = h;
}

// ---------------------------------------------------------------------------
// attn: MFMA flash attention — 128-token K-tiles (8 iterations, 16 barriers
// instead of 32: halves the per-barrier vmcnt drain overhead).
// Block = 256 thr (4 waves), 128 Q-rows, 2 row-tiles/wave; grid (8,8,8)=512.
// LDS: K/V 48 KB + P 18 KB = 66 KB -> 2 blocks/CU.  P LDS reused across the
// two 64-m halves of each tile (wave-private, program-order safe).
// log2-space softmax; row-sum l via ones-B-frag MFMA; P truncation.
// ---------------------------------------------------------------------------
__global__ __launch_bounds__(256) void attn_mfma(const short* __restrict__ qhi_g,
                                                 const short* __restrict__ qlo_g,
                                                 const short* __restrict__ khi_g,
                                                 const short* __restrict__ klo_g,
                                                 const short* __restrict__ vf_g,
                                                 short* __restrict__ ob) {
    __shared__ short Khi[8192], Klo[8192], Vf[8192];    // 16 chunks each
    __shared__ short Pbuf[4 * 64 * 36];
    const int b   = blockIdx.z;
    const int h   = blockIdx.y;
    const int tid = threadIdx.x;
    const int w    = tid >> 6;              // 4 waves
    const int lane = tid & 63;
    const int q    = lane >> 4;
    const int r    = lane & 15;
    short* Pw = Pbuf + w * (64 * 36);

    // Q fragments: direct 16B vector loads from the fused-emitted frag buffer
    short8 qhi[2][2], qlo[2][2];
    #pragma unroll
    for (int rt = 0; rt < 2; ++rt) {
        const int nt = blockIdx.x * 8 + w * 2 + rt;
        #pragma unroll
        for (int c = 0; c < 2; ++c) {
            size_t off = ((((size_t)(b * 8 + h) * 64 + nt) * 2 + c) * 64 + lane) * 8;
            qhi[rt][c] = *(const short8*)&qhi_g[off];
            qlo[rt][c] = *(const short8*)&qlo_g[off];
        }
    }

    short8 bones;
    #pragma unroll
    for (int j = 0; j < 8; ++j) bones[j] = (short)0x3F80;

    f32x4 oacc[2][4], lacc[2];
    float m_[2][4];
    #pragma unroll
    for (int rt = 0; rt < 2; ++rt) {
        #pragma unroll
        for (int tv = 0; tv < 4; ++tv) oacc[rt][tv] = (f32x4){0.f, 0.f, 0.f, 0.f};
        lacc[rt] = (f32x4){0.f, 0.f, 0.f, 0.f};
        #pragma unroll
        for (int i = 0; i < 4; ++i) m_[rt][i] = -1e30f;
    }

    for (int t = 0; t < 8; ++t) {           // 128-token tiles
        __syncthreads();
        const size_t kb = ((size_t)(b * 16 + t * 2) * 8) * 512;   // 16 chunks
        for (int ch = w; ch < 16; ch += 4) {
            dma16(khi_g + kb + ch * 512 + lane * 8, &Khi[ch * 512]);
            dma16(klo_g + kb + ch * 512 + lane * 8, &Klo[ch * 512]);
            dma16(vf_g  + kb + ch * 512 + lane * 8, &Vf [ch * 512]);
        }
        __syncthreads();

        // S (log2-scaled) = Q K^T over 128 K-tokens: 2rt x 8tt
        f32x4 s[2][8];
        #pragma unroll
        for (int rt = 0; rt < 2; ++rt)
            #pragma unroll
            for (int tt = 0; tt < 8; ++tt) s[rt][tt] = (f32x4){0.f, 0.f, 0.f, 0.f};
        #pragma unroll
        for (int c = 0; c < 2; ++c) {
            #pragma unroll
            for (int tt = 0; tt < 8; ++tt) {
                const int chunk = (tt >> 2) * 8 + (tt & 3) * 2 + c;
                short8 kh = *(short8*)&Khi[(chunk * 64 + lane) * 8];
                short8 kl = *(short8*)&Klo[(chunk * 64 + lane) * 8];
                #pragma unroll
                for (int rt = 0; rt < 2; ++rt) {
                    s[rt][tt] = __builtin_amdgcn_mfma_f32_16x16x32_bf16(qhi[rt][c], kh, s[rt][tt], 0, 0, 0);
                    s[rt][tt] = __builtin_amdgcn_mfma_f32_16x16x32_bf16(qhi[rt][c], kl, s[rt][tt], 0, 0, 0);
                    s[rt][tt] = __builtin_amdgcn_mfma_f32_16x16x32_bf16(qlo[rt][c], kh, s[rt][tt], 0, 0, 0);
                }
            }
        }

        // online softmax (log2 space) over 128 cols
        #pragma unroll
        for (int rt = 0; rt < 2; ++rt) {
            #pragma unroll
            for (int reg = 0; reg < 4; ++reg) {
                float smax = s[rt][0][reg];
                #pragma unroll
                for (int tt = 1; tt < 8; ++tt) smax = fmaxf(smax, s[rt][tt][reg]);
                #pragma unroll
                for (int off = 1; off < 16; off <<= 1)
                    smax = fmaxf(smax, __shfl_xor(smax, off, 16));
                float nm    = fmaxf(m_[rt][reg], smax);
                float alpha = exp2f(m_[rt][reg] - nm);
                m_[rt][reg] = nm;
                #pragma unroll
                for (int tt = 0; tt < 8; ++tt)
                    s[rt][tt][reg] = exp2f(s[rt][tt][reg] - nm);
                lacc[rt][reg] *= alpha;
                #pragma unroll
                for (int tv = 0; tv < 4; ++tv) oacc[rt][tv][reg] *= alpha;
            }
        }

        // P/PV in two 64-m halves (P LDS reused; wave-private, in-order)
        #pragma unroll
        for (int half = 0; half < 2; ++half) {
            #pragma unroll
            for (int rt = 0; rt < 2; ++rt) {
                #pragma unroll
                for (int tt4 = 0; tt4 < 4; ++tt4) {
                    short4v p4;
                    #pragma unroll
                    for (int reg = 0; reg < 4; ++reg)
                        p4[reg] = bf16tr(s[rt][half * 4 + tt4][reg]);
                    *(short4v*)&Pw[(r + 16 * tt4) * 36 + rt * 16 + q * 4] = p4;
                }
            }
            #pragma unroll
            for (int c2 = 0; c2 < 2; ++c2) {
                short8 pf[2];
                #pragma unroll
                for (int rt = 0; rt < 2; ++rt)
                    #pragma unroll
                    for (int j = 0; j < 8; ++j)
                        pf[rt][j] = Pw[(c2 * 32 + q * 8 + j) * 36 + rt * 16 + r];
                #pragma unroll
                for (int rt = 0; rt < 2; ++rt)
                    lacc[rt] = __builtin_amdgcn_mfma_f32_16x16x32_bf16(pf[rt], bones, lacc[rt], 0, 0, 0);
                #pragma unroll
                for (int tv = 0; tv < 4; ++tv) {
                    short8 vfr = *(short8*)&Vf[((half * 8 + tv * 2 + c2) * 64 + lane) * 8];
                    #pragma unroll
                    for (int rt = 0; rt < 2; ++rt)
                        oacc[rt][tv] = __builtin_amdgcn_mfma_f32_16x16x32_bf16(pf[rt], vfr, oacc[rt][tv], 0, 0, 0);
                }
            }
        }
    }

    // epilogue: normalize, write O as bf16 B-frags (layout verified R4-R9)
    #pragma unroll
    for (int rt = 0; rt < 2; ++rt) {
        const int nt = blockIdx.x * 8 + w * 2 + rt;
        #pragma unroll
        for (int reg = 0; reg < 4; ++reg) {
            float inv = 1.f / lacc[rt][reg];
            #pragma unroll
            for (int tv = 0; tv < 4; ++tv) {
                int ct = h * 2 + (tv >> 1);
                int lanep = ((tv & 1) * 2 + (r >> 3)) * 16 + q * 4 + reg;
                ob[((((size_t)b * 64 + nt) * 16 + ct) * 64 + lanep) * 8 + (r & 7)] =
                    bf16rn(oacc[rt][tv][reg] * inv);
            }
        }
    }
}

// ---------------------------------------------------------------------------
// out_gemm: plain bf16 MFMA, double-buffered staging (unchanged from R9).
// BM=64(d) BN=64(n) BK=64(c), 4 waves, grid (16,8,8)=1024 blocks; LDS 32 KB.
// ---------------------------------------------------------------------------
__global__ __launch_bounds__(256) void out_gemm(const short* __restrict__ wof,
                                                const short* __restrict__ obf,
                                                float* __restrict__ out) {
    __shared__ short Ah[2][4096];
    __shared__ short Bh[2][4096];
    const int b = blockIdx.z, bd = blockIdx.y, bn = blockIdx.x;
    const int tid = threadIdx.x, w = tid >> 6, lane = tid & 63;
    const int q = lane >> 4, r = lane & 15;
    f32x4 acc[4];
    #pragma unroll
    for (int j = 0; j < 4; ++j) acc[j] = (f32x4){0.f, 0.f, 0.f, 0.f};

    for (int u = w; u < 8; u += 4) {
        size_t ga = ((size_t)((bd * 4 + (u >> 1)) * 16 + (u & 1))) * 512 + lane * 8;
        dma16(wof + ga, &Ah[0][u * 512]);
        size_t gb = ((size_t)((b * 64 + bn * 4 + (u >> 1)) * 16 + (u & 1))) * 512 + lane * 8;
        dma16(obf + gb, &Bh[0][u * 512]);
    }

    for (int it = 0; it < 8; ++it) {
        const int cur = it & 1;
        __syncthreads();
        if (it < 7) {
            for (int u = w; u < 8; u += 4) {
                size_t ga = ((size_t)((bd * 4 + (u >> 1)) * 16 + (it + 1) * 2 + (u & 1))) * 512 + lane * 8;
                dma16(wof + ga, &Ah[cur ^ 1][u * 512]);
                size_t gb = ((size_t)((b * 64 + bn * 4 + (u >> 1)) * 16 + (it + 1) * 2 + (u & 1))) * 512 + lane * 8;
                dma16(obf + gb, &Bh[cur ^ 1][u * 512]);
            }
        }
        #pragma unroll
        for (int kc = 0; kc < 2; ++kc) {
            short8 a = *(short8*)&Ah[cur][(w * 2 + kc) * 512 + lane * 8];
            #pragma unroll
            for (int tt = 0; tt < 4; ++tt) {
                short8 bb = *(short8*)&Bh[cur][(tt * 2 + kc) * 512 + lane * 8];
                acc[tt] = __builtin_amdgcn_mfma_f32_16x16x32_bf16(a, bb, acc[tt], 0, 0, 0);
            }
        }
    }
    const int d_base = bd * 64 + w * 16;
    #pragma unroll
    for (int reg = 0; reg < 4; ++reg)
        #pragma unroll
        for (int tt = 0; tt < 4; ++tt)
            out[((size_t)b * DOUT + d_base + q * 4 + reg) * NTOK
                + bn * 64 + tt * 16 + r] = acc[tt][reg];
}

// ---------------------------------------------------------------------------
extern "C" void kernel_launch(void* const* d_in, const int* in_sizes, int n_in,
                              void* d_out, int out_size, void* d_ws, size_t ws_size,
                              hipStream_t stream) {
    const float* x  = (const float*)d_in[0];
    const float* qp = (const float*)d_in[1];
    const float* kp = (const float*)d_in[2];
    const float* vp = (const float*)d_in[3];
    const float* op = (const float*)d_in[4];
    float* out = (float*)d_out;

    // workspace layout: 38.0 MB (proven R9)
    short* Whi = (short*)d_ws;                 // 327,680
    short* Wlo = Whi + 327680;                 // 327,680
    short* Xhi = Wlo + 327680;                 // 4,194,304
    short* Xlo = Xhi + 4194304;                // 4,194,304
    short* Qhi = Xlo + 4194304;                // 4,194,304
    short* Qlo = Qhi + 4194304;                // 4,194,304
    short* Khi = Qlo + 4194304;                // 524,288
    short* Klo = Khi + 524288;                 // 524,288
    short* Vf  = Klo + 524288;                 // 524,288
    // aliases (safe by stream ordering; X dead after qkv_gemm):
    short* Ob  = Xhi;                          // attn output
    short* Wof = Xlo;                          // 262,144

    prepack_w   <<<160,  256, 0, stream>>>(qp, kp, vp, Whi, Wlo);
    prepack_x   <<<dim3(16, 8, BATCH), 256, 0, stream>>>(x, Xhi, Xlo);
    qkv_gemm    <<<dim3(10, 16, BATCH), 256, 0, stream>>>(Xhi, Xlo, Whi, Wlo,
                                                          Khi, Klo, Vf, Qhi, Qlo);
    prepack_wout<<<128,  256, 0, stream>>>(op, Wof);
    attn_mfma   <<<dim3(8, NH, BATCH), 256, 0, stream>>>(Qhi, Qlo, Khi, Klo, Vf, Ob);
    out_gemm    <<<dim3(16, 8, BATCH), 256, 0, stream>>>(Wof, Ob, out);
}

// Round 11
// 195.255 us; speedup vs baseline: 1.0969x; 1.0969x over previous
//
#include <hip/hip_runtime.h>
#include <math.h>

#define BATCH 8
#define DIMD  512
#define NTOK  1024
#define NH    8
#define CQKV  640
#define DOUT  512

typedef __attribute__((ext_vector_type(8))) short short8;
typedef __attribute__((ext_vector_type(4))) short short4v;
typedef __attribute__((ext_vector_type(4))) float f32x4;

__device__ __forceinline__ short bf16rn(float x) {
    unsigned u = __float_as_uint(x);
    u += 0x7FFF + ((u >> 16) & 1);
    return (short)(u >> 16);
}
__device__ __forceinline__ short bf16tr(float x) {
    return (short)(__float_as_uint(x) >> 16);
}
__device__ __forceinline__ float bf16tof(short s) {
    return __uint_as_float(((unsigned)(unsigned short)s) << 16);
}
struct HL { short h, l; };
__device__ __forceinline__ HL bf16split(float x) {
    HL r;
    r.h = bf16rn(x);
    r.l = bf16rn(x - bf16tof(r.h));
    return r;
}
__device__ __forceinline__ void dma16(const short* g, short* l) {
    __builtin_amdgcn_global_load_lds(
        (const __attribute__((address_space(1))) unsigned int*)g,
        (__attribute__((address_space(3))) unsigned int*)l, 16, 0, 0);
}

// Fragment-order conventions (verified end-to-end R2/R4-R10):
//  A-frag: lane=(q,r), element A[m=r][k=q*8+j] per 32-k chunk
//  B-frag: element B[ncol=r][k=q*8+j]
//  C/D   : D[m=q*4+reg][ncol=r]
// K/V frag buffers: [b][t16][ic8][lane64][j8]; Q: [b][h][nt64][kc2][lane64][j8]
// O frag buffer:    [b][nt64][ct16][lane64][j8], elem O[n=nt*16+r][c=ct*32+q*8+j]

// ---------------------------------------------------------------------------
__global__ void prepack_w(const float* __restrict__ qp, const float* __restrict__ kp,
                          const float* __restrict__ vp,
                          short* __restrict__ whi, short* __restrict__ wlo) {
    int tid = blockIdx.x * 256 + threadIdx.x;
    int lane = tid & 63, kt = (tid >> 6) & 15, ct = tid >> 10;
    int q = lane >> 4, r = lane & 15;
    int c = ct * 16 + r;
    short8 h, l;
    #pragma unroll
    for (int j = 0; j < 8; ++j) {
        int d = kt * 32 + q * 8 + j;
        float v;
        if (c < 64)       v = kp[d * 64 + c];
        else if (c < 128) v = vp[d * 64 + (c - 64)];
        else              v = qp[(size_t)(c - 128) * DIMD + d];
        HL s = bf16split(v);
        h[j] = s.h; l[j] = s.l;
    }
    *(short8*)&whi[(size_t)tid * 8] = h;
    *(short8*)&wlo[(size_t)tid * 8] = l;
}

// ---------------------------------------------------------------------------
// prepack_x: coalesced LDS-transpose (R10, kept: saved ~3 µs)
// ---------------------------------------------------------------------------
__global__ __launch_bounds__(256) void prepack_x(const float* __restrict__ x,
                                                 short* __restrict__ xhi,
                                                 short* __restrict__ xlo) {
    __shared__ float Cs[64][65];
    const int b = blockIdx.z, dt = blockIdx.y, nt = blockIdx.x;
    const int t = threadIdx.x;
    #pragma unroll
    for (int i = 0; i < 4; ++i) {
        int row = (t >> 4) + i * 16;
        float4 v = *(const float4*)(x + ((size_t)(b * DIMD + dt * 64 + row)) * NTOK
                                      + nt * 64 + (t & 15) * 4);
        Cs[row][(t & 15) * 4 + 0] = v.x;
        Cs[row][(t & 15) * 4 + 1] = v.y;
        Cs[row][(t & 15) * 4 + 2] = v.z;
        Cs[row][(t & 15) * 4 + 3] = v.w;
    }
    __syncthreads();
    for (int u = t; u < 512; u += 256) {
        int lane2 = u & 63, cidx = u >> 6;
        int q2 = lane2 >> 4, r2 = lane2 & 15;
        int kt_loc = cidx & 1, mt_loc = cidx >> 1;
        short8 h8, l8;
        #pragma unroll
        for (int j = 0; j < 8; ++j) {
            HL s = bf16split(Cs[kt_loc * 32 + q2 * 8 + j][mt_loc * 16 + r2]);
            h8[j] = s.h; l8[j] = s.l;
        }
        size_t off = (((size_t)(b * 64 + nt * 4 + mt_loc)) * 16 + dt * 2 + kt_loc) * 512
                     + lane2 * 8;
        *(short8*)&xhi[off] = h8;
        *(short8*)&xlo[off] = l8;
    }
}

// ---------------------------------------------------------------------------
// qkv_gemm: split-bf16 MFMA + fused frag emission (unchanged from R9/R10)
// ---------------------------------------------------------------------------
__global__ __launch_bounds__(256) void qkv_gemm(const short* __restrict__ xhi,
                                                const short* __restrict__ xlo,
                                                const short* __restrict__ whi,
                                                const short* __restrict__ wlo,
                                                short* __restrict__ khi,
                                                short* __restrict__ klo,
                                                short* __restrict__ vf,
                                                short* __restrict__ qhi,
                                                short* __restrict__ qlo) {
    __shared__ __align__(16) char pool[32768];
    short* Ah = (short*)pool;
    short* Al = Ah + 4096;
    short* Bh = Al + 4096;
    short* Bl = Bh + 4096;
    float (*Cs)[65] = (float(*)[65])pool;

    const int b = blockIdx.z, bm = blockIdx.y, cb = blockIdx.x;
    const int tid = threadIdx.x, w = tid >> 6, lane = tid & 63;
    const int q = lane >> 4, r = lane & 15;
    f32x4 acc[4];
    #pragma unroll
    for (int j = 0; j < 4; ++j) acc[j] = (f32x4){0.f, 0.f, 0.f, 0.f};

    for (int it = 0; it < 8; ++it) {
        __syncthreads();
        for (int u = w; u < 8; u += 4) {
            size_t ga = ((size_t)((b * 64 + bm * 4 + (u >> 1)) * 16 + it * 2 + (u & 1))) * 512 + lane * 8;
            dma16(xhi + ga, &Ah[u * 512]);
            dma16(xlo + ga, &Al[u * 512]);
            size_t gb = ((size_t)((cb * 4 + (u >> 1)) * 16 + it * 2 + (u & 1))) * 512 + lane * 8;
            dma16(whi + gb, &Bh[u * 512]);
            dma16(wlo + gb, &Bl[u * 512]);
        }
        __syncthreads();
        #pragma unroll
        for (int kc = 0; kc < 2; ++kc) {
            short8 ah = *(short8*)&Ah[(w * 2 + kc) * 512 + lane * 8];
            short8 al = *(short8*)&Al[(w * 2 + kc) * 512 + lane * 8];
            #pragma unroll
            for (int tt = 0; tt < 4; ++tt) {
                short8 bh = *(short8*)&Bh[(tt * 2 + kc) * 512 + lane * 8];
                short8 bl = *(short8*)&Bl[(tt * 2 + kc) * 512 + lane * 8];
                acc[tt] = __builtin_amdgcn_mfma_f32_16x16x32_bf16(ah, bh, acc[tt], 0, 0, 0);
                acc[tt] = __builtin_amdgcn_mfma_f32_16x16x32_bf16(ah, bl, acc[tt], 0, 0, 0);
                acc[tt] = __builtin_amdgcn_mfma_f32_16x16x32_bf16(al, bh, acc[tt], 0, 0, 0);
            }
        }
    }

    __syncthreads();
    #pragma unroll
    for (int reg = 0; reg < 4; ++reg)
        #pragma unroll
        for (int tt = 0; tt < 4; ++tt)
            Cs[w * 16 + q * 4 + reg][tt * 16 + r] = acc[tt][reg];
    __syncthreads();

    if (cb == 0) {
        for (int u = tid; u < 512; u += 256) {
            int lane2 = u & 63, ic = u >> 6;
            int q2 = lane2 >> 4, r2 = lane2 & 15;
            int i = ic >> 1, cc = ic & 1;
            short8 h8, l8;
            #pragma unroll
            for (int j = 0; j < 8; ++j) {
                HL s = bf16split(Cs[i * 16 + r2][cc * 32 + q2 * 8 + j]);
                h8[j] = s.h; l8[j] = s.l;
            }
            size_t off = ((size_t)(b * 16 + bm) * 8 + ic) * 512 + lane2 * 8;
            *(short8*)&khi[off] = h8;
            *(short8*)&klo[off] = l8;
        }
    } else if (cb == 1) {
        for (int u = tid; u < 512; u += 256) {
            int lane2 = u & 63, ic = u >> 6;
            int q2 = lane2 >> 4, r2 = lane2 & 15;
            int tv = ic >> 1, cc = ic & 1;
            short8 v8;
            #pragma unroll
            for (int j = 0; j < 8; ++j)
                v8[j] = bf16rn(Cs[cc * 32 + q2 * 8 + j][tv * 16 + r2]);
            size_t off = ((size_t)(b * 16 + bm) * 8 + ic) * 512 + lane2 * 8;
            *(short8*)&vf[off] = v8;
        }
    } else {
        const int hd = cb - 2;
        const float qscale = 0.125f * 1.44269504f;
        for (int u = tid; u < 512; u += 256) {
            int lane2 = u & 63, ic = u >> 6;
            int q2 = lane2 >> 4, r2 = lane2 & 15;
            int ntl = ic >> 1, kc = ic & 1;
            short8 h8, l8;
            #pragma unroll
            for (int j = 0; j < 8; ++j) {
                HL s = bf16split(Cs[ntl * 16 + r2][kc * 32 + q2 * 8 + j] * qscale);
                h8[j] = s.h; l8[j] = s.l;
            }
            size_t off = ((((size_t)(b * 8 + hd) * 64 + bm * 4 + ntl) * 2 + kc) * 64 + lane2) * 8;
            *(short8*)&qhi[off] = h8;
            *(short8*)&qlo[off] = l8;
        }
    }
}

// ---------------------------------------------------------------------------
__global__ void prepack_wout(const float* __restrict__ wout, short* __restrict__ wof) {
    int tid = blockIdx.x * 256 + threadIdx.x;
    int lane = tid & 63, kt = (tid >> 6) & 15, mt = tid >> 10;
    int q = lane >> 4, r = lane & 15;
    const float* src = wout + (size_t)(mt * 16 + r) * DOUT + kt * 32 + q * 8;
    short8 h;
    #pragma unroll
    for (int j = 0; j < 8; ++j) h[j] = bf16rn(src[j]);
    *(short8*)&wof[(size_t)tid * 8] = h;
}

// ---------------------------------------------------------------------------
// attn: split-K flash attention.  R9 inner loop (proven 75 µs) over HALF the
// tokens per block; grid (16,8,8)=1024 -> 4 blocks/CU to hide barrier drains.
// blockIdx.x: qt = x&7, split = x>>3; tiles t = split*8 .. split*8+7.
// Epilogue writes UNNORMALIZED O (bf16 B-frags) to opart[split] and per-row
// (m, l) float2 to lm[((b*8+h)*2+split)*1024 + n].
// ---------------------------------------------------------------------------
__global__ __launch_bounds__(256) void attn_mfma(const short* __restrict__ qhi_g,
                                                 const short* __restrict__ qlo_g,
                                                 const short* __restrict__ khi_g,
                                                 const short* __restrict__ klo_g,
                                                 const short* __restrict__ vf_g,
                                                 short* __restrict__ opart0,
                                                 short* __restrict__ opart1,
                                                 float2* __restrict__ lm) {
    __shared__ short Khi[4096], Klo[4096], Vf[4096];
    __shared__ short Pbuf[4 * 64 * 36];
    const int b     = blockIdx.z;
    const int h     = blockIdx.y;
    const int qt    = blockIdx.x & 7;
    const int split = blockIdx.x >> 3;
    const int tid = threadIdx.x;
    const int w    = tid >> 6;
    const int lane = tid & 63;
    const int q    = lane >> 4;
    const int r    = lane & 15;
    short* Pw = Pbuf + w * (64 * 36);
    short* ob = split ? opart1 : opart0;

    short8 qhi[2][2], qlo[2][2];
    #pragma unroll
    for (int rt = 0; rt < 2; ++rt) {
        const int nt = qt * 8 + w * 2 + rt;
        #pragma unroll
        for (int c = 0; c < 2; ++c) {
            size_t off = ((((size_t)(b * 8 + h) * 64 + nt) * 2 + c) * 64 + lane) * 8;
            qhi[rt][c] = *(const short8*)&qhi_g[off];
            qlo[rt][c] = *(const short8*)&qlo_g[off];
        }
    }

    short8 bones;
    #pragma unroll
    for (int j = 0; j < 8; ++j) bones[j] = (short)0x3F80;

    f32x4 oacc[2][4], lacc[2];
    float m_[2][4];
    #pragma unroll
    for (int rt = 0; rt < 2; ++rt) {
        #pragma unroll
        for (int tt = 0; tt < 4; ++tt) oacc[rt][tt] = (f32x4){0.f, 0.f, 0.f, 0.f};
        lacc[rt] = (f32x4){0.f, 0.f, 0.f, 0.f};
        #pragma unroll
        for (int i = 0; i < 4; ++i) m_[rt][i] = -1e30f;
    }

    for (int t = 0; t < 8; ++t) {
        __syncthreads();
        const size_t kb = ((size_t)(b * 16 + split * 8 + t) * 8) * 512;
        for (int ch = w; ch < 8; ch += 4) {
            dma16(khi_g + kb + ch * 512 + lane * 8, &Khi[ch * 512]);
            dma16(klo_g + kb + ch * 512 + lane * 8, &Klo[ch * 512]);
            dma16(vf_g  + kb + ch * 512 + lane * 8, &Vf [ch * 512]);
        }
        __syncthreads();

        f32x4 s[2][4];
        #pragma unroll
        for (int rt = 0; rt < 2; ++rt)
            #pragma unroll
            for (int tt = 0; tt < 4; ++tt) s[rt][tt] = (f32x4){0.f, 0.f, 0.f, 0.f};
        #pragma unroll
        for (int c = 0; c < 2; ++c) {
            #pragma unroll
            for (int tt = 0; tt < 4; ++tt) {
                short8 kh = *(short8*)&Khi[((tt * 2 + c) * 64 + lane) * 8];
                short8 kl = *(short8*)&Klo[((tt * 2 + c) * 64 + lane) * 8];
                #pragma unroll
                for (int rt = 0; rt < 2; ++rt) {
                    s[rt][tt] = __builtin_amdgcn_mfma_f32_16x16x32_bf16(qhi[rt][c], kh, s[rt][tt], 0, 0, 0);
                    s[rt][tt] = __builtin_amdgcn_mfma_f32_16x16x32_bf16(qhi[rt][c], kl, s[rt][tt], 0, 0, 0);
                    s[rt][tt] = __builtin_amdgcn_mfma_f32_16x16x32_bf16(qlo[rt][c], kh, s[rt][tt], 0, 0, 0);
                }
            }
        }

        #pragma unroll
        for (int rt = 0; rt < 2; ++rt) {
            #pragma unroll
            for (int reg = 0; reg < 4; ++reg) {
                float smax = fmaxf(fmaxf(s[rt][0][reg], s[rt][1][reg]),
                                   fmaxf(s[rt][2][reg], s[rt][3][reg]));
                #pragma unroll
                for (int off = 1; off < 16; off <<= 1)
                    smax = fmaxf(smax, __shfl_xor(smax, off, 16));
                float nm    = fmaxf(m_[rt][reg], smax);
                float alpha = exp2f(m_[rt][reg] - nm);
                m_[rt][reg] = nm;
                #pragma unroll
                for (int tt = 0; tt < 4; ++tt)
                    s[rt][tt][reg] = exp2f(s[rt][tt][reg] - nm);
                lacc[rt][reg] *= alpha;
                #pragma unroll
                for (int tt = 0; tt < 4; ++tt) oacc[rt][tt][reg] *= alpha;
            }
        }

        #pragma unroll
        for (int rt = 0; rt < 2; ++rt) {
            #pragma unroll
            for (int tt = 0; tt < 4; ++tt) {
                short4v p4;
                #pragma unroll
                for (int reg = 0; reg < 4; ++reg) p4[reg] = bf16tr(s[rt][tt][reg]);
                *(short4v*)&Pw[(r + 16 * tt) * 36 + rt * 16 + q * 4] = p4;
            }
        }

        #pragma unroll
        for (int c = 0; c < 2; ++c) {
            short8 pf[2];
            #pragma unroll
            for (int rt = 0; rt < 2; ++rt)
                #pragma unroll
                for (int j = 0; j < 8; ++j)
                    pf[rt][j] = Pw[(c * 32 + q * 8 + j) * 36 + rt * 16 + r];
            #pragma unroll
            for (int rt = 0; rt < 2; ++rt)
                lacc[rt] = __builtin_amdgcn_mfma_f32_16x16x32_bf16(pf[rt], bones, lacc[rt], 0, 0, 0);
            #pragma unroll
            for (int tt = 0; tt < 4; ++tt) {
                short8 vfr = *(short8*)&Vf[((tt * 2 + c) * 64 + lane) * 8];
                #pragma unroll
                for (int rt = 0; rt < 2; ++rt)
                    oacc[rt][tt] = __builtin_amdgcn_mfma_f32_16x16x32_bf16(pf[rt], vfr, oacc[rt][tt], 0, 0, 0);
            }
        }
    }

    // epilogue: UNNORMALIZED O -> opart[split]; (m,l) per row -> lm
    #pragma unroll
    for (int rt = 0; rt < 2; ++rt) {
        const int nt = qt * 8 + w * 2 + rt;
        #pragma unroll
        for (int reg = 0; reg < 4; ++reg) {
            #pragma unroll
            for (int tt = 0; tt < 4; ++tt) {
                int ct = h * 2 + (tt >> 1);
                int lanep = ((tt & 1) * 2 + (r >> 3)) * 16 + q * 4 + reg;
                ob[((((size_t)b * 64 + nt) * 16 + ct) * 64 + lanep) * 8 + (r & 7)] =
                    bf16rn(oacc[rt][tt][reg]);
            }
            if (r == 0) {
                int n = nt * 16 + q * 4 + reg;
                lm[(((size_t)(b * 8 + h) * 2 + split)) * 1024 + n] =
                    make_float2(m_[rt][reg], lacc[rt][reg]);
            }
        }
    }
}

// ---------------------------------------------------------------------------
// merge_splits: Ob = (O1*2^(m1-m) + O2*2^(m2-m)) / (l1*2^(m1-m)+l2*2^(m2-m))
// One thread per short8 group of the O frag buffer (524,288 threads).
// ---------------------------------------------------------------------------
__global__ __launch_bounds__(256) void merge_splits(const short* __restrict__ o1,
                                                    const short* __restrict__ o2,
                                                    const float2* __restrict__ lm,
                                                    short* __restrict__ ob) {
    int idx = blockIdx.x * 256 + threadIdx.x;       // 524288
    int lane2 = idx & 63, ct = (idx >> 6) & 15, nt = (idx >> 10) & 63, b = idx >> 16;
    int n = nt * 16 + (lane2 & 15);
    int h = ct >> 1;
    float2 ml1 = lm[(((size_t)(b * 8 + h) * 2 + 0)) * 1024 + n];
    float2 ml2 = lm[(((size_t)(b * 8 + h) * 2 + 1)) * 1024 + n];
    float m  = fmaxf(ml1.x, ml2.x);
    float s1 = exp2f(ml1.x - m), s2 = exp2f(ml2.x - m);
    float inv = 1.f / (ml1.y * s1 + ml2.y * s2);
    float w1 = s1 * inv, w2 = s2 * inv;
    short8 a = *(const short8*)&o1[(size_t)idx * 8];
    short8 c = *(const short8*)&o2[(size_t)idx * 8];
    short8 o;
    #pragma unroll
    for (int j = 0; j < 8; ++j)
        o[j] = bf16rn(bf16tof(a[j]) * w1 + bf16tof(c[j]) * w2);
    *(short8*)&ob[(size_t)idx * 8] = o;
}

// ---------------------------------------------------------------------------
// out_gemm: plain bf16 MFMA, double-buffered staging (unchanged).
// ---------------------------------------------------------------------------
__global__ __launch_bounds__(256) void out_gemm(const short* __restrict__ wof,
                                                const short* __restrict__ obf,
                                                float* __restrict__ out) {
    __shared__ short Ah[2][4096];
    __shared__ short Bh[2][4096];
    const int b = blockIdx.z, bd = blockIdx.y, bn = blockIdx.x;
    const int tid = threadIdx.x, w = tid >> 6, lane = tid & 63;
    const int q = lane >> 4, r = lane & 15;
    f32x4 acc[4];
    #pragma unroll
    for (int j = 0; j < 4; ++j) acc[j] = (f32x4){0.f, 0.f, 0.f, 0.f};

    for (int u = w; u < 8; u += 4) {
        size_t ga = ((size_t)((bd * 4 + (u >> 1)) * 16 + (u & 1))) * 512 + lane * 8;
        dma16(wof + ga, &Ah[0][u * 512]);
        size_t gb = ((size_t)((b * 64 + bn * 4 + (u >> 1)) * 16 + (u & 1))) * 512 + lane * 8;
        dma16(obf + gb, &Bh[0][u * 512]);
    }

    for (int it = 0; it < 8; ++it) {
        const int cur = it & 1;
        __syncthreads();
        if (it < 7) {
            for (int u = w; u < 8; u += 4) {
                size_t ga = ((size_t)((bd * 4 + (u >> 1)) * 16 + (it + 1) * 2 + (u & 1))) * 512 + lane * 8;
                dma16(wof + ga, &Ah[cur ^ 1][u * 512]);
                size_t gb = ((size_t)((b * 64 + bn * 4 + (u >> 1)) * 16 + (it + 1) * 2 + (u & 1))) * 512 + lane * 8;
                dma16(obf + gb, &Bh[cur ^ 1][u * 512]);
            }
        }
        #pragma unroll
        for (int kc = 0; kc < 2; ++kc) {
            short8 a = *(short8*)&Ah[cur][(w * 2 + kc) * 512 + lane * 8];
            #pragma unroll
            for (int tt = 0; tt < 4; ++tt) {
                short8 bb = *(short8*)&Bh[cur][(tt * 2 + kc) * 512 + lane * 8];
                acc[tt] = __builtin_amdgcn_mfma_f32_16x16x32_bf16(a, bb, acc[tt], 0, 0, 0);
            }
        }
    }
    const int d_base = bd * 64 + w * 16;
    #pragma unroll
    for (int reg = 0; reg < 4; ++reg)
        #pragma unroll
        for (int tt = 0; tt < 4; ++tt)
            out[((size_t)b * DOUT + d_base + q * 4 + reg) * NTOK
                + bn * 64 + tt * 16 + r] = acc[tt][reg];
}

// ---------------------------------------------------------------------------
extern "C" void kernel_launch(void* const* d_in, const int* in_sizes, int n_in,
                              void* d_out, int out_size, void* d_ws, size_t ws_size,
                              hipStream_t stream) {
    const float* x  = (const float*)d_in[0];
    const float* qp = (const float*)d_in[1];
    const float* kp = (const float*)d_in[2];
    const float* vp = (const float*)d_in[3];
    const float* op = (const float*)d_in[4];
    float* out = (float*)d_out;

    // workspace: 19,529,728 shorts = 39.06 MB (== R1-proven footprint)
    short* Whi = (short*)d_ws;                 // 327,680   (dead after qkv_gemm)
    short* Wlo = Whi + 327680;                 // 327,680   (dead after qkv_gemm)
    short* Xhi = Wlo + 327680;                 // 4,194,304 (dead after qkv_gemm)
    short* Xlo = Xhi + 4194304;                // 4,194,304 (dead after qkv_gemm)
    short* Qhi = Xlo + 4194304;                // 4,194,304 (dead after attn)
    short* Qlo = Qhi + 4194304;                // 4,194,304 (dead after attn)
    short* Khi = Qlo + 4194304;                // 524,288
    short* Klo = Khi + 524288;                 // 524,288
    short* Vf  = Klo + 524288;                 // 524,288
    float2* Lm = (float2*)(Vf + 524288);       // 131,072 float2 = 1 MB
    // aliases (stream-ordered):
    short* Wof    = Whi;                       // prepack_wout after qkv_gemm
    short* Opart0 = Xhi;                       // attn split-0 output
    short* Opart1 = Xlo;                       // attn split-1 output
    short* Obm    = Qhi;                       // merged O (after attn)

    prepack_w   <<<160,  256, 0, stream>>>(qp, kp, vp, Whi, Wlo);
    prepack_x   <<<dim3(16, 8, BATCH), 256, 0, stream>>>(x, Xhi, Xlo);
    qkv_gemm    <<<dim3(10, 16, BATCH), 256, 0, stream>>>(Xhi, Xlo, Whi, Wlo,
                                                          Khi, Klo, Vf, Qhi, Qlo);
    prepack_wout<<<128,  256, 0, stream>>>(op, Wof);
    attn_mfma   <<<dim3(16, NH, BATCH), 256, 0, stream>>>(Qhi, Qlo, Khi, Klo, Vf,
                                                          Opart0, Opart1, Lm);
    merge_splits<<<2048, 256, 0, stream>>>(Opart0, Opart1, Lm, Obm);
    out_gemm    <<<dim3(16, 8, BATCH), 256, 0, stream>>>(Wof, Obm, out);
}

// Round 12
// 181.912 us; speedup vs baseline: 1.1774x; 1.0733x over previous
//
#include <hip/hip_runtime.h>
#include <math.h>

#define BATCH 8
#define DIMD  512
#define NTOK  1024
#define NH    8
#define CQKV  640
#define DOUT  512

typedef __attribute__((ext_vector_type(8))) short short8;
typedef __attribute__((ext_vector_type(4))) short short4v;
typedef __attribute__((ext_vector_type(4))) float f32x4;

__device__ __forceinline__ short bf16rn(float x) {
    unsigned u = __float_as_uint(x);
    u += 0x7FFF + ((u >> 16) & 1);
    return (short)(u >> 16);
}
__device__ __forceinline__ float bf16tof(short s) {
    return __uint_as_float(((unsigned)(unsigned short)s) << 16);
}
struct HL { short h, l; };
__device__ __forceinline__ HL bf16split(float x) {
    HL r;
    r.h = bf16rn(x);
    r.l = bf16rn(x - bf16tof(r.h));
    return r;
}
__device__ __forceinline__ void dma16(const short* g, short* l) {
    __builtin_amdgcn_global_load_lds(
        (const __attribute__((address_space(1))) unsigned int*)g,
        (__attribute__((address_space(3))) unsigned int*)l, 16, 0, 0);
}
// max over the 16-lane r-group (lanes with equal q): ds_swizzle xor 1,2,4,8
__device__ __forceinline__ float swzmax16(float v) {
    v = fmaxf(v, __int_as_float(__builtin_amdgcn_ds_swizzle(__float_as_int(v), 0x041F)));
    v = fmaxf(v, __int_as_float(__builtin_amdgcn_ds_swizzle(__float_as_int(v), 0x081F)));
    v = fmaxf(v, __int_as_float(__builtin_amdgcn_ds_swizzle(__float_as_int(v), 0x101F)));
    v = fmaxf(v, __int_as_float(__builtin_amdgcn_ds_swizzle(__float_as_int(v), 0x201F)));
    return v;
}
// pack (truncate) two f32 -> two bf16 in one dword: low = f0>>16, high = f1>>16
__device__ __forceinline__ unsigned packbf2(float f0, float f1) {
    return __builtin_amdgcn_perm(__float_as_uint(f1), __float_as_uint(f0), 0x07060302);
}

// Fragment-order conventions (verified end-to-end R2/R4-R11):
//  A-frag: lane=(q,r), element A[m=r][k=q*8+j] per 32-k chunk
//  B-frag: element B[ncol=r][k=q*8+j]
//  C/D   : D[m=q*4+reg][ncol=r]
// K/V frag buffers: [b][t16][ic8][lane64][j8]; Q: [b][h][nt64][kc2][lane64][j8]
// O frag buffer:    [b][nt64][ct16][lane64][j8]

// ---------------------------------------------------------------------------
// prepack_all: fused prepack_w (blocks 1024-1183) + prepack_x (0-1023) +
// prepack_wout (1184-1311).  One launch instead of three.
// ---------------------------------------------------------------------------
__global__ __launch_bounds__(256) void prepack_all(const float* __restrict__ x,
                                                   const float* __restrict__ qp,
                                                   const float* __restrict__ kp,
                                                   const float* __restrict__ vp,
                                                   const float* __restrict__ wout,
                                                   short* __restrict__ whi,
                                                   short* __restrict__ wlo,
                                                   short* __restrict__ xhi,
                                                   short* __restrict__ xlo,
                                                   short* __restrict__ wof) {
    __shared__ float Cs[64][65];
    const int blk = blockIdx.x;
    const int t = threadIdx.x;
    if (blk < 1024) {
        // ---- prepack_x: coalesced LDS-transpose (R10 form, kept) ----
        const int nt = blk & 15, dt = (blk >> 4) & 7, b = blk >> 7;
        #pragma unroll
        for (int i = 0; i < 4; ++i) {
            int row = (t >> 4) + i * 16;
            float4 v = *(const float4*)(x + ((size_t)(b * DIMD + dt * 64 + row)) * NTOK
                                          + nt * 64 + (t & 15) * 4);
            Cs[row][(t & 15) * 4 + 0] = v.x;
            Cs[row][(t & 15) * 4 + 1] = v.y;
            Cs[row][(t & 15) * 4 + 2] = v.z;
            Cs[row][(t & 15) * 4 + 3] = v.w;
        }
        __syncthreads();
        for (int u = t; u < 512; u += 256) {
            int lane2 = u & 63, cidx = u >> 6;
            int q2 = lane2 >> 4, r2 = lane2 & 15;
            int kt_loc = cidx & 1, mt_loc = cidx >> 1;
            short8 h8, l8;
            #pragma unroll
            for (int j = 0; j < 8; ++j) {
                HL s = bf16split(Cs[kt_loc * 32 + q2 * 8 + j][mt_loc * 16 + r2]);
                h8[j] = s.h; l8[j] = s.l;
            }
            size_t off = (((size_t)(b * 64 + nt * 4 + mt_loc)) * 16 + dt * 2 + kt_loc) * 512
                         + lane2 * 8;
            *(short8*)&xhi[off] = h8;
            *(short8*)&xlo[off] = l8;
        }
    } else if (blk < 1184) {
        // ---- prepack_w ----
        int tid = (blk - 1024) * 256 + t;               // 40960
        int lane = tid & 63, kt = (tid >> 6) & 15, ct = tid >> 10;
        int q = lane >> 4, r = lane & 15;
        int c = ct * 16 + r;
        short8 h, l;
        #pragma unroll
        for (int j = 0; j < 8; ++j) {
            int d = kt * 32 + q * 8 + j;
            float v;
            if (c < 64)       v = kp[d * 64 + c];
            else if (c < 128) v = vp[d * 64 + (c - 64)];
            else              v = qp[(size_t)(c - 128) * DIMD + d];
            HL s = bf16split(v);
            h[j] = s.h; l[j] = s.l;
        }
        *(short8*)&whi[(size_t)tid * 8] = h;
        *(short8*)&wlo[(size_t)tid * 8] = l;
    } else {
        // ---- prepack_wout ----
        int tid = (blk - 1184) * 256 + t;               // 32768
        int lane = tid & 63, kt = (tid >> 6) & 15, mt = tid >> 10;
        int q = lane >> 4, r = lane & 15;
        const float* src = wout + (size_t)(mt * 16 + r) * DOUT + kt * 32 + q * 8;
        short8 h;
        #pragma unroll
        for (int j = 0; j < 8; ++j) h[j] = bf16rn(src[j]);
        *(short8*)&wof[(size_t)tid * 8] = h;
    }
}

// ---------------------------------------------------------------------------
// qkv_gemm: split-bf16 MFMA + fused frag emission (unchanged from R9-R11)
// ---------------------------------------------------------------------------
__global__ __launch_bounds__(256) void qkv_gemm(const short* __restrict__ xhi,
                                                const short* __restrict__ xlo,
                                                const short* __restrict__ whi,
                                                const short* __restrict__ wlo,
                                                short* __restrict__ khi,
                                                short* __restrict__ klo,
                                                short* __restrict__ vf,
                                                short* __restrict__ qhi,
                                                short* __restrict__ qlo) {
    __shared__ __align__(16) char pool[32768];
    short* Ah = (short*)pool;
    short* Al = Ah + 4096;
    short* Bh = Al + 4096;
    short* Bl = Bh + 4096;
    float (*Cs)[65] = (float(*)[65])pool;

    const int b = blockIdx.z, bm = blockIdx.y, cb = blockIdx.x;
    const int tid = threadIdx.x, w = tid >> 6, lane = tid & 63;
    const int q = lane >> 4, r = lane & 15;
    f32x4 acc[4];
    #pragma unroll
    for (int j = 0; j < 4; ++j) acc[j] = (f32x4){0.f, 0.f, 0.f, 0.f};

    for (int it = 0; it < 8; ++it) {
        __syncthreads();
        for (int u = w; u < 8; u += 4) {
            size_t ga = ((size_t)((b * 64 + bm * 4 + (u >> 1)) * 16 + it * 2 + (u & 1))) * 512 + lane * 8;
            dma16(xhi + ga, &Ah[u * 512]);
            dma16(xlo + ga, &Al[u * 512]);
            size_t gb = ((size_t)((cb * 4 + (u >> 1)) * 16 + it * 2 + (u & 1))) * 512 + lane * 8;
            dma16(whi + gb, &Bh[u * 512]);
            dma16(wlo + gb, &Bl[u * 512]);
        }
        __syncthreads();
        #pragma unroll
        for (int kc = 0; kc < 2; ++kc) {
            short8 ah = *(short8*)&Ah[(w * 2 + kc) * 512 + lane * 8];
            short8 al = *(short8*)&Al[(w * 2 + kc) * 512 + lane * 8];
            #pragma unroll
            for (int tt = 0; tt < 4; ++tt) {
                short8 bh = *(short8*)&Bh[(tt * 2 + kc) * 512 + lane * 8];
                short8 bl = *(short8*)&Bl[(tt * 2 + kc) * 512 + lane * 8];
                acc[tt] = __builtin_amdgcn_mfma_f32_16x16x32_bf16(ah, bh, acc[tt], 0, 0, 0);
                acc[tt] = __builtin_amdgcn_mfma_f32_16x16x32_bf16(ah, bl, acc[tt], 0, 0, 0);
                acc[tt] = __builtin_amdgcn_mfma_f32_16x16x32_bf16(al, bh, acc[tt], 0, 0, 0);
            }
        }
    }

    __syncthreads();
    #pragma unroll
    for (int reg = 0; reg < 4; ++reg)
        #pragma unroll
        for (int tt = 0; tt < 4; ++tt)
            Cs[w * 16 + q * 4 + reg][tt * 16 + r] = acc[tt][reg];
    __syncthreads();

    if (cb == 0) {
        for (int u = tid; u < 512; u += 256) {
            int lane2 = u & 63, ic = u >> 6;
            int q2 = lane2 >> 4, r2 = lane2 & 15;
            int i = ic >> 1, cc = ic & 1;
            short8 h8, l8;
            #pragma unroll
            for (int j = 0; j < 8; ++j) {
                HL s = bf16split(Cs[i * 16 + r2][cc * 32 + q2 * 8 + j]);
                h8[j] = s.h; l8[j] = s.l;
            }
            size_t off = ((size_t)(b * 16 + bm) * 8 + ic) * 512 + lane2 * 8;
            *(short8*)&khi[off] = h8;
            *(short8*)&klo[off] = l8;
        }
    } else if (cb == 1) {
        for (int u = tid; u < 512; u += 256) {
            int lane2 = u & 63, ic = u >> 6;
            int q2 = lane2 >> 4, r2 = lane2 & 15;
            int tv = ic >> 1, cc = ic & 1;
            short8 v8;
            #pragma unroll
            for (int j = 0; j < 8; ++j)
                v8[j] = bf16rn(Cs[cc * 32 + q2 * 8 + j][tv * 16 + r2]);
            size_t off = ((size_t)(b * 16 + bm) * 8 + ic) * 512 + lane2 * 8;
            *(short8*)&vf[off] = v8;
        }
    } else {
        const int hd = cb - 2;
        const float qscale = 0.125f * 1.44269504f;
        for (int u = tid; u < 512; u += 256) {
            int lane2 = u & 63, ic = u >> 6;
            int q2 = lane2 >> 4, r2 = lane2 & 15;
            int ntl = ic >> 1, kc = ic & 1;
            short8 h8, l8;
            #pragma unroll
            for (int j = 0; j < 8; ++j) {
                HL s = bf16split(Cs[ntl * 16 + r2][kc * 32 + q2 * 8 + j] * qscale);
                h8[j] = s.h; l8[j] = s.l;
            }
            size_t off = ((((size_t)(b * 8 + hd) * 64 + bm * 4 + ntl) * 2 + kc) * 64 + lane2) * 8;
            *(short8*)&qhi[off] = h8;
            *(short8*)&qlo[off] = l8;
        }
    }
}

// ---------------------------------------------------------------------------
// attn: MFMA flash attention — R9 structure (proven best, 75 µs), 1D grid
// with XCD-aware mapping (b = blk&7 so one batch's K/V stays in one XCD L2).
// Row-max via ds_swizzle (1 DS inst/step); P packed via v_perm_b32.
// ---------------------------------------------------------------------------
__global__ __launch_bounds__(256) void attn_mfma(const short* __restrict__ qhi_g,
                                                 const short* __restrict__ qlo_g,
                                                 const short* __restrict__ khi_g,
                                                 const short* __restrict__ klo_g,
                                                 const short* __restrict__ vf_g,
                                                 short* __restrict__ ob) {
    __shared__ short Khi[4096], Klo[4096], Vf[4096];
    __shared__ short Pbuf[4 * 64 * 36];
    const int blk = blockIdx.x;             // 512 = 8b x 8h x 8qt
    const int b   = blk & 7;
    const int h   = (blk >> 3) & 7;
    const int qt  = blk >> 6;
    const int tid = threadIdx.x;
    const int w    = tid >> 6;
    const int lane = tid & 63;
    const int q    = lane >> 4;
    const int r    = lane & 15;
    short* Pw = Pbuf + w * (64 * 36);

    short8 qhi[2][2], qlo[2][2];
    #pragma unroll
    for (int rt = 0; rt < 2; ++rt) {
        const int nt = qt * 8 + w * 2 + rt;
        #pragma unroll
        for (int c = 0; c < 2; ++c) {
            size_t off = ((((size_t)(b * 8 + h) * 64 + nt) * 2 + c) * 64 + lane) * 8;
            qhi[rt][c] = *(const short8*)&qhi_g[off];
            qlo[rt][c] = *(const short8*)&qlo_g[off];
        }
    }

    short8 bones;
    #pragma unroll
    for (int j = 0; j < 8; ++j) bones[j] = (short)0x3F80;

    f32x4 oacc[2][4], lacc[2];
    float m_[2][4];
    #pragma unroll
    for (int rt = 0; rt < 2; ++rt) {
        #pragma unroll
        for (int tt = 0; tt < 4; ++tt) oacc[rt][tt] = (f32x4){0.f, 0.f, 0.f, 0.f};
        lacc[rt] = (f32x4){0.f, 0.f, 0.f, 0.f};
        #pragma unroll
        for (int i = 0; i < 4; ++i) m_[rt][i] = -1e30f;
    }

    for (int t = 0; t < 16; ++t) {
        __syncthreads();
        const size_t kb = ((size_t)(b * 16 + t) * 8) * 512;
        for (int ch = w; ch < 8; ch += 4) {
            dma16(khi_g + kb + ch * 512 + lane * 8, &Khi[ch * 512]);
            dma16(klo_g + kb + ch * 512 + lane * 8, &Klo[ch * 512]);
            dma16(vf_g  + kb + ch * 512 + lane * 8, &Vf [ch * 512]);
        }
        __syncthreads();

        f32x4 s[2][4];
        #pragma unroll
        for (int rt = 0; rt < 2; ++rt)
            #pragma unroll
            for (int tt = 0; tt < 4; ++tt) s[rt][tt] = (f32x4){0.f, 0.f, 0.f, 0.f};
        #pragma unroll
        for (int c = 0; c < 2; ++c) {
            #pragma unroll
            for (int tt = 0; tt < 4; ++tt) {
                short8 kh = *(short8*)&Khi[((tt * 2 + c) * 64 + lane) * 8];
                short8 kl = *(short8*)&Klo[((tt * 2 + c) * 64 + lane) * 8];
                #pragma unroll
                for (int rt = 0; rt < 2; ++rt) {
                    s[rt][tt] = __builtin_amdgcn_mfma_f32_16x16x32_bf16(qhi[rt][c], kh, s[rt][tt], 0, 0, 0);
                    s[rt][tt] = __builtin_amdgcn_mfma_f32_16x16x32_bf16(qhi[rt][c], kl, s[rt][tt], 0, 0, 0);
                    s[rt][tt] = __builtin_amdgcn_mfma_f32_16x16x32_bf16(qlo[rt][c], kh, s[rt][tt], 0, 0, 0);
                }
            }
        }

        // online softmax (log2 space): ds_swizzle row-max; sum via ones-MFMA
        #pragma unroll
        for (int rt = 0; rt < 2; ++rt) {
            #pragma unroll
            for (int reg = 0; reg < 4; ++reg) {
                float smax = fmaxf(fmaxf(s[rt][0][reg], s[rt][1][reg]),
                                   fmaxf(s[rt][2][reg], s[rt][3][reg]));
                smax = swzmax16(smax);
                float nm    = fmaxf(m_[rt][reg], smax);
                float alpha = exp2f(m_[rt][reg] - nm);
                m_[rt][reg] = nm;
                #pragma unroll
                for (int tt = 0; tt < 4; ++tt)
                    s[rt][tt][reg] = exp2f(s[rt][tt][reg] - nm);
                lacc[rt][reg] *= alpha;
                #pragma unroll
                for (int tt = 0; tt < 4; ++tt) oacc[rt][tt][reg] *= alpha;
            }
        }

        // P -> per-wave LDS (col-major, stride 36); v_perm packing, b64 writes
        #pragma unroll
        for (int rt = 0; rt < 2; ++rt) {
            #pragma unroll
            for (int tt = 0; tt < 4; ++tt) {
                uint2 pk;
                pk.x = packbf2(s[rt][tt][0], s[rt][tt][1]);
                pk.y = packbf2(s[rt][tt][2], s[rt][tt][3]);
                *(uint2*)&Pw[(r + 16 * tt) * 36 + rt * 16 + q * 4] = pk;
            }
        }

        #pragma unroll
        for (int c = 0; c < 2; ++c) {
            short8 pf[2];
            #pragma unroll
            for (int rt = 0; rt < 2; ++rt)
                #pragma unroll
                for (int j = 0; j < 8; ++j)
                    pf[rt][j] = Pw[(c * 32 + q * 8 + j) * 36 + rt * 16 + r];
            #pragma unroll
            for (int rt = 0; rt < 2; ++rt)
                lacc[rt] = __builtin_amdgcn_mfma_f32_16x16x32_bf16(pf[rt], bones, lacc[rt], 0, 0, 0);
            #pragma unroll
            for (int tt = 0; tt < 4; ++tt) {
                short8 vfr = *(short8*)&Vf[((tt * 2 + c) * 64 + lane) * 8];
                #pragma unroll
                for (int rt = 0; rt < 2; ++rt)
                    oacc[rt][tt] = __builtin_amdgcn_mfma_f32_16x16x32_bf16(pf[rt], vfr, oacc[rt][tt], 0, 0, 0);
            }
        }
    }

    #pragma unroll
    for (int rt = 0; rt < 2; ++rt) {
        const int nt = qt * 8 + w * 2 + rt;
        #pragma unroll
        for (int reg = 0; reg < 4; ++reg) {
            float inv = 1.f / lacc[rt][reg];
            #pragma unroll
            for (int tt = 0; tt < 4; ++tt) {
                int ct = h * 2 + (tt >> 1);
                int lanep = ((tt & 1) * 2 + (r >> 3)) * 16 + q * 4 + reg;
                ob[((((size_t)b * 64 + nt) * 16 + ct) * 64 + lanep) * 8 + (r & 7)] =
                    bf16rn(oacc[rt][tt][reg] * inv);
            }
        }
    }
}

// ---------------------------------------------------------------------------
// out_gemm: plain bf16 MFMA, double-buffered staging (unchanged).
// ---------------------------------------------------------------------------
__global__ __launch_bounds__(256) void out_gemm(const short* __restrict__ wof,
                                                const short* __restrict__ obf,
                                                float* __restrict__ out) {
    __shared__ short Ah[2][4096];
    __shared__ short Bh[2][4096];
    const int b = blockIdx.z, bd = blockIdx.y, bn = blockIdx.x;
    const int tid = threadIdx.x, w = tid >> 6, lane = tid & 63;
    const int q = lane >> 4, r = lane & 15;
    f32x4 acc[4];
    #pragma unroll
    for (int j = 0; j < 4; ++j) acc[j] = (f32x4){0.f, 0.f, 0.f, 0.f};

    for (int u = w; u < 8; u += 4) {
        size_t ga = ((size_t)((bd * 4 + (u >> 1)) * 16 + (u & 1))) * 512 + lane * 8;
        dma16(wof + ga, &Ah[0][u * 512]);
        size_t gb = ((size_t)((b * 64 + bn * 4 + (u >> 1)) * 16 + (u & 1))) * 512 + lane * 8;
        dma16(obf + gb, &Bh[0][u * 512]);
    }

    for (int it = 0; it < 8; ++it) {
        const int cur = it & 1;
        __syncthreads();
        if (it < 7) {
            for (int u = w; u < 8; u += 4) {
                size_t ga = ((size_t)((bd * 4 + (u >> 1)) * 16 + (it + 1) * 2 + (u & 1))) * 512 + lane * 8;
                dma16(wof + ga, &Ah[cur ^ 1][u * 512]);
                size_t gb = ((size_t)((b * 64 + bn * 4 + (u >> 1)) * 16 + (it + 1) * 2 + (u & 1))) * 512 + lane * 8;
                dma16(obf + gb, &Bh[cur ^ 1][u * 512]);
            }
        }
        #pragma unroll
        for (int kc = 0; kc < 2; ++kc) {
            short8 a = *(short8*)&Ah[cur][(w * 2 + kc) * 512 + lane * 8];
            #pragma unroll
            for (int tt = 0; tt < 4; ++tt) {
                short8 bb = *(short8*)&Bh[cur][(tt * 2 + kc) * 512 + lane * 8];
                acc[tt] = __builtin_amdgcn_mfma_f32_16x16x32_bf16(a, bb, acc[tt], 0, 0, 0);
            }
        }
    }
    const int d_base = bd * 64 + w * 16;
    #pragma unroll
    for (int reg = 0; reg < 4; ++reg)
        #pragma unroll
        for (int tt = 0; tt < 4; ++tt)
            out[((size_t)b * DOUT + d_base + q * 4 + reg) * NTOK
                + bn * 64 + tt * 16 + r] = acc[tt][reg];
}

// ---------------------------------------------------------------------------
extern "C" void kernel_launch(void* const* d_in, const int* in_sizes, int n_in,
                              void* d_out, int out_size, void* d_ws, size_t ws_size,
                              hipStream_t stream) {
    const float* x  = (const float*)d_in[0];
    const float* qp = (const float*)d_in[1];
    const float* kp = (const float*)d_in[2];
    const float* vp = (const float*)d_in[3];
    const float* op = (const float*)d_in[4];
    float* out = (float*)d_out;

    // workspace: 19,267,584 shorts = 38.5 MB (< proven 39.06 MB)
    short* Whi = (short*)d_ws;                 // 327,680
    short* Wlo = Whi + 327680;                 // 327,680
    short* Xhi = Wlo + 327680;                 // 4,194,304
    short* Xlo = Xhi + 4194304;                // 4,194,304
    short* Qhi = Xlo + 4194304;                // 4,194,304
    short* Qlo = Qhi + 4194304;                // 4,194,304
    short* Khi = Qlo + 4194304;                // 524,288
    short* Klo = Khi + 524288;                 // 524,288
    short* Vf  = Klo + 524288;                 // 524,288
    short* Wof = Vf  + 524288;                 // 262,144 (own slot: written pre-qkv)
    // alias (stream-ordered; X dead after qkv_gemm):
    short* Ob  = Xhi;

    prepack_all <<<1312, 256, 0, stream>>>(x, qp, kp, vp, op,
                                           Whi, Wlo, Xhi, Xlo, Wof);
    qkv_gemm    <<<dim3(10, 16, BATCH), 256, 0, stream>>>(Xhi, Xlo, Whi, Wlo,
                                                          Khi, Klo, Vf, Qhi, Qlo);
    attn_mfma   <<<512, 256, 0, stream>>>(Qhi, Qlo, Khi, Klo, Vf, Ob);
    out_gemm    <<<dim3(16, 8, BATCH), 256, 0, stream>>>(Wof, Ob, out);
}

// Round 13
// 173.893 us; speedup vs baseline: 1.2317x; 1.0461x over previous
//
#include <hip/hip_runtime.h>
#include <math.h>

#define BATCH 8
#define DIMD  512
#define NTOK  1024
#define NH    8
#define CQKV  640
#define DOUT  512

typedef __attribute__((ext_vector_type(8))) short short8;
typedef __attribute__((ext_vector_type(4))) short short4v;
typedef __attribute__((ext_vector_type(4))) float f32x4;

__device__ __forceinline__ short bf16rn(float x) {
    unsigned u = __float_as_uint(x);
    u += 0x7FFF + ((u >> 16) & 1);
    return (short)(u >> 16);
}
__device__ __forceinline__ float bf16tof(short s) {
    return __uint_as_float(((unsigned)(unsigned short)s) << 16);
}
struct HL { short h, l; };
__device__ __forceinline__ HL bf16split(float x) {
    HL r;
    r.h = bf16rn(x);
    r.l = bf16rn(x - bf16tof(r.h));
    return r;
}
__device__ __forceinline__ void dma16(const short* g, short* l) {
    __builtin_amdgcn_global_load_lds(
        (const __attribute__((address_space(1))) unsigned int*)g,
        (__attribute__((address_space(3))) unsigned int*)l, 16, 0, 0);
}
// max over the 16-lane r-group: ds_swizzle xor 1,2,4,8
__device__ __forceinline__ float swzmax16(float v) {
    v = fmaxf(v, __int_as_float(__builtin_amdgcn_ds_swizzle(__float_as_int(v), 0x041F)));
    v = fmaxf(v, __int_as_float(__builtin_amdgcn_ds_swizzle(__float_as_int(v), 0x081F)));
    v = fmaxf(v, __int_as_float(__builtin_amdgcn_ds_swizzle(__float_as_int(v), 0x101F)));
    v = fmaxf(v, __int_as_float(__builtin_amdgcn_ds_swizzle(__float_as_int(v), 0x201F)));
    return v;
}
// pack (truncate) two f32 -> two bf16 in one dword
__device__ __forceinline__ unsigned packbf2(float f0, float f1) {
    return __builtin_amdgcn_perm(__float_as_uint(f1), __float_as_uint(f0), 0x07060302);
}

// Fragment-order conventions (verified end-to-end R2/R4-R12):
//  A-frag: lane=(q,r), element A[m=r][k=q*8+j] per 32-k chunk
//  B-frag: element B[ncol=r][k=q*8+j]
//  C/D   : D[m=q*4+reg][ncol=r]
// K/V frag buffers: [b][t16][ic8][lane64][j8]; Q: [b][h][nt64][kc2][lane64][j8]
// O frag buffer:    [b][nt64][ct16][lane64][j8]

// ---------------------------------------------------------------------------
// prepack_all: fused prepack_x (blocks 0-1023) + prepack_w (1024-1183) +
// prepack_wout (1184-1311).
// ---------------------------------------------------------------------------
__global__ __launch_bounds__(256) void prepack_all(const float* __restrict__ x,
                                                   const float* __restrict__ qp,
                                                   const float* __restrict__ kp,
                                                   const float* __restrict__ vp,
                                                   const float* __restrict__ wout,
                                                   short* __restrict__ whi,
                                                   short* __restrict__ wlo,
                                                   short* __restrict__ xhi,
                                                   short* __restrict__ xlo,
                                                   short* __restrict__ wof) {
    __shared__ float Cs[64][65];
    const int blk = blockIdx.x;
    const int t = threadIdx.x;
    if (blk < 1024) {
        const int nt = blk & 15, dt = (blk >> 4) & 7, b = blk >> 7;
        #pragma unroll
        for (int i = 0; i < 4; ++i) {
            int row = (t >> 4) + i * 16;
            float4 v = *(const float4*)(x + ((size_t)(b * DIMD + dt * 64 + row)) * NTOK
                                          + nt * 64 + (t & 15) * 4);
            Cs[row][(t & 15) * 4 + 0] = v.x;
            Cs[row][(t & 15) * 4 + 1] = v.y;
            Cs[row][(t & 15) * 4 + 2] = v.z;
            Cs[row][(t & 15) * 4 + 3] = v.w;
        }
        __syncthreads();
        for (int u = t; u < 512; u += 256) {
            int lane2 = u & 63, cidx = u >> 6;
            int q2 = lane2 >> 4, r2 = lane2 & 15;
            int kt_loc = cidx & 1, mt_loc = cidx >> 1;
            short8 h8, l8;
            #pragma unroll
            for (int j = 0; j < 8; ++j) {
                HL s = bf16split(Cs[kt_loc * 32 + q2 * 8 + j][mt_loc * 16 + r2]);
                h8[j] = s.h; l8[j] = s.l;
            }
            size_t off = (((size_t)(b * 64 + nt * 4 + mt_loc)) * 16 + dt * 2 + kt_loc) * 512
                         + lane2 * 8;
            *(short8*)&xhi[off] = h8;
            *(short8*)&xlo[off] = l8;
        }
    } else if (blk < 1184) {
        int tid = (blk - 1024) * 256 + t;
        int lane = tid & 63, kt = (tid >> 6) & 15, ct = tid >> 10;
        int q = lane >> 4, r = lane & 15;
        int c = ct * 16 + r;
        short8 h, l;
        #pragma unroll
        for (int j = 0; j < 8; ++j) {
            int d = kt * 32 + q * 8 + j;
            float v;
            if (c < 64)       v = kp[d * 64 + c];
            else if (c < 128) v = vp[d * 64 + (c - 64)];
            else              v = qp[(size_t)(c - 128) * DIMD + d];
            HL s = bf16split(v);
            h[j] = s.h; l[j] = s.l;
        }
        *(short8*)&whi[(size_t)tid * 8] = h;
        *(short8*)&wlo[(size_t)tid * 8] = l;
    } else {
        int tid = (blk - 1184) * 256 + t;
        int lane = tid & 63, kt = (tid >> 6) & 15, mt = tid >> 10;
        int q = lane >> 4, r = lane & 15;
        const float* src = wout + (size_t)(mt * 16 + r) * DOUT + kt * 32 + q * 8;
        short8 h;
        #pragma unroll
        for (int j = 0; j < 8; ++j) h[j] = bf16rn(src[j]);
        *(short8*)&wof[(size_t)tid * 8] = h;
    }
}

// ---------------------------------------------------------------------------
// qkv_gemm: split-bf16 MFMA + fused frag emission.  1D grid with XCD-aware
// swizzle: all 10 cb-blocks of one (b,bm) group (sharing the X A-tile) map to
// the same XCD (idx%8 == group%8).
// ---------------------------------------------------------------------------
__global__ __launch_bounds__(256) void qkv_gemm(const short* __restrict__ xhi,
                                                const short* __restrict__ xlo,
                                                const short* __restrict__ whi,
                                                const short* __restrict__ wlo,
                                                short* __restrict__ khi,
                                                short* __restrict__ klo,
                                                short* __restrict__ vf,
                                                short* __restrict__ qhi,
                                                short* __restrict__ qlo) {
    __shared__ __align__(16) char pool[32768];
    short* Ah = (short*)pool;
    short* Al = Ah + 4096;
    short* Bh = Al + 4096;
    short* Bl = Bh + 4096;
    float (*Cs)[65] = (float(*)[65])pool;

    // XCD swizzle decode: idx = (g%8) + 8*((g>>3)*10 + cb), g = b*16+bm
    const int idx = blockIdx.x;
    const int low = idx & 7, rest = idx >> 3;
    const int cb = rest % 10, gh = rest / 10;
    const int g = gh * 8 + low;
    const int b = g >> 4, bm = g & 15;

    const int tid = threadIdx.x, w = tid >> 6, lane = tid & 63;
    const int q = lane >> 4, r = lane & 15;
    f32x4 acc[4];
    #pragma unroll
    for (int j = 0; j < 4; ++j) acc[j] = (f32x4){0.f, 0.f, 0.f, 0.f};

    for (int it = 0; it < 8; ++it) {
        __syncthreads();
        for (int u = w; u < 8; u += 4) {
            size_t ga = ((size_t)((b * 64 + bm * 4 + (u >> 1)) * 16 + it * 2 + (u & 1))) * 512 + lane * 8;
            dma16(xhi + ga, &Ah[u * 512]);
            dma16(xlo + ga, &Al[u * 512]);
            size_t gb = ((size_t)((cb * 4 + (u >> 1)) * 16 + it * 2 + (u & 1))) * 512 + lane * 8;
            dma16(whi + gb, &Bh[u * 512]);
            dma16(wlo + gb, &Bl[u * 512]);
        }
        __syncthreads();
        #pragma unroll
        for (int kc = 0; kc < 2; ++kc) {
            short8 ah = *(short8*)&Ah[(w * 2 + kc) * 512 + lane * 8];
            short8 al = *(short8*)&Al[(w * 2 + kc) * 512 + lane * 8];
            #pragma unroll
            for (int tt = 0; tt < 4; ++tt) {
                short8 bh = *(short8*)&Bh[(tt * 2 + kc) * 512 + lane * 8];
                short8 bl = *(short8*)&Bl[(tt * 2 + kc) * 512 + lane * 8];
                acc[tt] = __builtin_amdgcn_mfma_f32_16x16x32_bf16(ah, bh, acc[tt], 0, 0, 0);
                acc[tt] = __builtin_amdgcn_mfma_f32_16x16x32_bf16(ah, bl, acc[tt], 0, 0, 0);
                acc[tt] = __builtin_amdgcn_mfma_f32_16x16x32_bf16(al, bh, acc[tt], 0, 0, 0);
            }
        }
    }

    __syncthreads();
    #pragma unroll
    for (int reg = 0; reg < 4; ++reg)
        #pragma unroll
        for (int tt = 0; tt < 4; ++tt)
            Cs[w * 16 + q * 4 + reg][tt * 16 + r] = acc[tt][reg];
    __syncthreads();

    if (cb == 0) {
        for (int u = tid; u < 512; u += 256) {
            int lane2 = u & 63, ic = u >> 6;
            int q2 = lane2 >> 4, r2 = lane2 & 15;
            int i = ic >> 1, cc = ic & 1;
            short8 h8, l8;
            #pragma unroll
            for (int j = 0; j < 8; ++j) {
                HL s = bf16split(Cs[i * 16 + r2][cc * 32 + q2 * 8 + j]);
                h8[j] = s.h; l8[j] = s.l;
            }
            size_t off = ((size_t)(b * 16 + bm) * 8 + ic) * 512 + lane2 * 8;
            *(short8*)&khi[off] = h8;
            *(short8*)&klo[off] = l8;
        }
    } else if (cb == 1) {
        for (int u = tid; u < 512; u += 256) {
            int lane2 = u & 63, ic = u >> 6;
            int q2 = lane2 >> 4, r2 = lane2 & 15;
            int tv = ic >> 1, cc = ic & 1;
            short8 v8;
            #pragma unroll
            for (int j = 0; j < 8; ++j)
                v8[j] = bf16rn(Cs[cc * 32 + q2 * 8 + j][tv * 16 + r2]);
            size_t off = ((size_t)(b * 16 + bm) * 8 + ic) * 512 + lane2 * 8;
            *(short8*)&vf[off] = v8;
        }
    } else {
        const int hd = cb - 2;
        const float qscale = 0.125f * 1.44269504f;
        for (int u = tid; u < 512; u += 256) {
            int lane2 = u & 63, ic = u >> 6;
            int q2 = lane2 >> 4, r2 = lane2 & 15;
            int ntl = ic >> 1, kc = ic & 1;
            short8 h8, l8;
            #pragma unroll
            for (int j = 0; j < 8; ++j) {
                HL s = bf16split(Cs[ntl * 16 + r2][kc * 32 + q2 * 8 + j] * qscale);
                h8[j] = s.h; l8[j] = s.l;
            }
            size_t off = ((((size_t)(b * 8 + hd) * 64 + bm * 4 + ntl) * 2 + kc) * 64 + lane2) * 8;
            *(short8*)&qhi[off] = h8;
            *(short8*)&qlo[off] = l8;
        }
    }
}

// ---------------------------------------------------------------------------
// attn: MFMA flash attention — R12 structure + LAZY softmax rescaling.
// The final O/l ratio is independent of the reference max m̂ (both carry the
// same exp2(-m̂) factor), so m̂ only needs to stay within ~±30 of the true
// max to avoid fp32 over/underflow.  Per tile: cheap per-lane partial max;
// full swizzle-reduce + rescale only when __any lane sees pmax > m̂+30
// (wave-uniform branch; skip path is EXACTLY alpha=1).  Tile 0 always
// triggers (m̂=-1e30).
// ---------------------------------------------------------------------------
__global__ __launch_bounds__(256) void attn_mfma(const short* __restrict__ qhi_g,
                                                 const short* __restrict__ qlo_g,
                                                 const short* __restrict__ khi_g,
                                                 const short* __restrict__ klo_g,
                                                 const short* __restrict__ vf_g,
                                                 short* __restrict__ ob) {
    __shared__ short Khi[4096], Klo[4096], Vf[4096];
    __shared__ short Pbuf[4 * 64 * 36];
    const int blk = blockIdx.x;             // 512 = 8b x 8h x 8qt, b in low bits
    const int b   = blk & 7;
    const int h   = (blk >> 3) & 7;
    const int qt  = blk >> 6;
    const int tid = threadIdx.x;
    const int w    = tid >> 6;
    const int lane = tid & 63;
    const int q    = lane >> 4;
    const int r    = lane & 15;
    short* Pw = Pbuf + w * (64 * 36);

    short8 qhi[2][2], qlo[2][2];
    #pragma unroll
    for (int rt = 0; rt < 2; ++rt) {
        const int nt = qt * 8 + w * 2 + rt;
        #pragma unroll
        for (int c = 0; c < 2; ++c) {
            size_t off = ((((size_t)(b * 8 + h) * 64 + nt) * 2 + c) * 64 + lane) * 8;
            qhi[rt][c] = *(const short8*)&qhi_g[off];
            qlo[rt][c] = *(const short8*)&qlo_g[off];
        }
    }

    short8 bones;
    #pragma unroll
    for (int j = 0; j < 8; ++j) bones[j] = (short)0x3F80;

    f32x4 oacc[2][4], lacc[2];
    float m_[2][4];
    #pragma unroll
    for (int rt = 0; rt < 2; ++rt) {
        #pragma unroll
        for (int tt = 0; tt < 4; ++tt) oacc[rt][tt] = (f32x4){0.f, 0.f, 0.f, 0.f};
        lacc[rt] = (f32x4){0.f, 0.f, 0.f, 0.f};
        #pragma unroll
        for (int i = 0; i < 4; ++i) m_[rt][i] = -1e30f;
    }

    for (int t = 0; t < 16; ++t) {
        __syncthreads();
        const size_t kb = ((size_t)(b * 16 + t) * 8) * 512;
        for (int ch = w; ch < 8; ch += 4) {
            dma16(khi_g + kb + ch * 512 + lane * 8, &Khi[ch * 512]);
            dma16(klo_g + kb + ch * 512 + lane * 8, &Klo[ch * 512]);
            dma16(vf_g  + kb + ch * 512 + lane * 8, &Vf [ch * 512]);
        }
        __syncthreads();

        f32x4 s[2][4];
        #pragma unroll
        for (int rt = 0; rt < 2; ++rt)
            #pragma unroll
            for (int tt = 0; tt < 4; ++tt) s[rt][tt] = (f32x4){0.f, 0.f, 0.f, 0.f};
        #pragma unroll
        for (int c = 0; c < 2; ++c) {
            #pragma unroll
            for (int tt = 0; tt < 4; ++tt) {
                short8 kh = *(short8*)&Khi[((tt * 2 + c) * 64 + lane) * 8];
                short8 kl = *(short8*)&Klo[((tt * 2 + c) * 64 + lane) * 8];
                #pragma unroll
                for (int rt = 0; rt < 2; ++rt) {
                    s[rt][tt] = __builtin_amdgcn_mfma_f32_16x16x32_bf16(qhi[rt][c], kh, s[rt][tt], 0, 0, 0);
                    s[rt][tt] = __builtin_amdgcn_mfma_f32_16x16x32_bf16(qhi[rt][c], kl, s[rt][tt], 0, 0, 0);
                    s[rt][tt] = __builtin_amdgcn_mfma_f32_16x16x32_bf16(qlo[rt][c], kh, s[rt][tt], 0, 0, 0);
                }
            }
        }

        // ---- lazy online softmax (log2 space) ----
        float pmax[2][4];
        bool need = false;
        #pragma unroll
        for (int rt = 0; rt < 2; ++rt)
            #pragma unroll
            for (int reg = 0; reg < 4; ++reg) {
                float pm = fmaxf(fmaxf(s[rt][0][reg], s[rt][1][reg]),
                                 fmaxf(s[rt][2][reg], s[rt][3][reg]));
                pmax[rt][reg] = pm;
                need = need || (pm > m_[rt][reg] + 30.f);
            }
        if (__any((int)need)) {
            // full path: swizzle-reduce max, update m̂, rescale state
            #pragma unroll
            for (int rt = 0; rt < 2; ++rt)
                #pragma unroll
                for (int reg = 0; reg < 4; ++reg) {
                    float smax = swzmax16(pmax[rt][reg]);
                    float nm    = fmaxf(m_[rt][reg], smax);
                    float alpha = exp2f(m_[rt][reg] - nm);
                    m_[rt][reg] = nm;
                    lacc[rt][reg] *= alpha;
                    #pragma unroll
                    for (int tt = 0; tt < 4; ++tt) oacc[rt][tt][reg] *= alpha;
                }
        }
        // common: exponentiate against current m̂ (skip path == alpha 1)
        #pragma unroll
        for (int rt = 0; rt < 2; ++rt)
            #pragma unroll
            for (int reg = 0; reg < 4; ++reg)
                #pragma unroll
                for (int tt = 0; tt < 4; ++tt)
                    s[rt][tt][reg] = exp2f(s[rt][tt][reg] - m_[rt][reg]);

        // P -> per-wave LDS (col-major, stride 36); v_perm packing, b64 writes
        #pragma unroll
        for (int rt = 0; rt < 2; ++rt) {
            #pragma unroll
            for (int tt = 0; tt < 4; ++tt) {
                uint2 pk;
                pk.x = packbf2(s[rt][tt][0], s[rt][tt][1]);
                pk.y = packbf2(s[rt][tt][2], s[rt][tt][3]);
                *(uint2*)&Pw[(r + 16 * tt) * 36 + rt * 16 + q * 4] = pk;
            }
        }

        #pragma unroll
        for (int c = 0; c < 2; ++c) {
            short8 pf[2];
            #pragma unroll
            for (int rt = 0; rt < 2; ++rt)
                #pragma unroll
                for (int j = 0; j < 8; ++j)
                    pf[rt][j] = Pw[(c * 32 + q * 8 + j) * 36 + rt * 16 + r];
            #pragma unroll
            for (int rt = 0; rt < 2; ++rt)
                lacc[rt] = __builtin_amdgcn_mfma_f32_16x16x32_bf16(pf[rt], bones, lacc[rt], 0, 0, 0);
            #pragma unroll
            for (int tt = 0; tt < 4; ++tt) {
                short8 vfr = *(short8*)&Vf[((tt * 2 + c) * 64 + lane) * 8];
                #pragma unroll
                for (int rt = 0; rt < 2; ++rt)
                    oacc[rt][tt] = __builtin_amdgcn_mfma_f32_16x16x32_bf16(pf[rt], vfr, oacc[rt][tt], 0, 0, 0);
            }
        }
    }

    #pragma unroll
    for (int rt = 0; rt < 2; ++rt) {
        const int nt = qt * 8 + w * 2 + rt;
        #pragma unroll
        for (int reg = 0; reg < 4; ++reg) {
            float inv = 1.f / lacc[rt][reg];
            #pragma unroll
            for (int tt = 0; tt < 4; ++tt) {
                int ct = h * 2 + (tt >> 1);
                int lanep = ((tt & 1) * 2 + (r >> 3)) * 16 + q * 4 + reg;
                ob[((((size_t)b * 64 + nt) * 16 + ct) * 64 + lanep) * 8 + (r & 7)] =
                    bf16rn(oacc[rt][tt][reg] * inv);
            }
        }
    }
}

// ---------------------------------------------------------------------------
// out_gemm: plain bf16 MFMA, double-buffered staging (unchanged).
// ---------------------------------------------------------------------------
__global__ __launch_bounds__(256) void out_gemm(const short* __restrict__ wof,
                                                const short* __restrict__ obf,
                                                float* __restrict__ out) {
    __shared__ short Ah[2][4096];
    __shared__ short Bh[2][4096];
    const int b = blockIdx.z, bd = blockIdx.y, bn = blockIdx.x;
    const int tid = threadIdx.x, w = tid >> 6, lane = tid & 63;
    const int q = lane >> 4, r = lane & 15;
    f32x4 acc[4];
    #pragma unroll
    for (int j = 0; j < 4; ++j) acc[j] = (f32x4){0.f, 0.f, 0.f, 0.f};

    for (int u = w; u < 8; u += 4) {
        size_t ga = ((size_t)((bd * 4 + (u >> 1)) * 16 + (u & 1))) * 512 + lane * 8;
        dma16(wof + ga, &Ah[0][u * 512]);
        size_t gb = ((size_t)((b * 64 + bn * 4 + (u >> 1)) * 16 + (u & 1))) * 512 + lane * 8;
        dma16(obf + gb, &Bh[0][u * 512]);
    }

    for (int it = 0; it < 8; ++it) {
        const int cur = it & 1;
        __syncthreads();
        if (it < 7) {
            for (int u = w; u < 8; u += 4) {
                size_t ga = ((size_t)((bd * 4 + (u >> 1)) * 16 + (it + 1) * 2 + (u & 1))) * 512 + lane * 8;
                dma16(wof + ga, &Ah[cur ^ 1][u * 512]);
                size_t gb = ((size_t)((b * 64 + bn * 4 + (u >> 1)) * 16 + (it + 1) * 2 + (u & 1))) * 512 + lane * 8;
                dma16(obf + gb, &Bh[cur ^ 1][u * 512]);
            }
        }
        #pragma unroll
        for (int kc = 0; kc < 2; ++kc) {
            short8 a = *(short8*)&Ah[cur][(w * 2 + kc) * 512 + lane * 8];
            #pragma unroll
            for (int tt = 0; tt < 4; ++tt) {
                short8 bb = *(short8*)&Bh[cur][(tt * 2 + kc) * 512 + lane * 8];
                acc[tt] = __builtin_amdgcn_mfma_f32_16x16x32_bf16(a, bb, acc[tt], 0, 0, 0);
            }
        }
    }
    const int d_base = bd * 64 + w * 16;
    #pragma unroll
    for (int reg = 0; reg < 4; ++reg)
        #pragma unroll
        for (int tt = 0; tt < 4; ++tt)
            out[((size_t)b * DOUT + d_base + q * 4 + reg) * NTOK
                + bn * 64 + tt * 16 + r] = acc[tt][reg];
}

// ---------------------------------------------------------------------------
extern "C" void kernel_launch(void* const* d_in, const int* in_sizes, int n_in,
                              void* d_out, int out_size, void* d_ws, size_t ws_size,
                              hipStream_t stream) {
    const float* x  = (const float*)d_in[0];
    const float* qp = (const float*)d_in[1];
    const float* kp = (const float*)d_in[2];
    const float* vp = (const float*)d_in[3];
    const float* op = (const float*)d_in[4];
    float* out = (float*)d_out;

    // workspace: 38.5 MB (proven R12)
    short* Whi = (short*)d_ws;                 // 327,680
    short* Wlo = Whi + 327680;                 // 327,680
    short* Xhi = Wlo + 327680;                 // 4,194,304
    short* Xlo = Xhi + 4194304;                // 4,194,304
    short* Qhi = Xlo + 4194304;                // 4,194,304
    short* Qlo = Qhi + 4194304;                // 4,194,304
    short* Khi = Qlo + 4194304;                // 524,288
    short* Klo = Khi + 524288;                 // 524,288
    short* Vf  = Klo + 524288;                 // 524,288
    short* Wof = Vf  + 524288;                 // 262,144
    short* Ob  = Xhi;                          // alias: X dead after qkv_gemm

    prepack_all <<<1312, 256, 0, stream>>>(x, qp, kp, vp, op,
                                           Whi, Wlo, Xhi, Xlo, Wof);
    qkv_gemm    <<<1280, 256, 0, stream>>>(Xhi, Xlo, Whi, Wlo,
                                           Khi, Klo, Vf, Qhi, Qlo);
    attn_mfma   <<<512, 256, 0, stream>>>(Qhi, Qlo, Khi, Klo, Vf, Ob);
    out_gemm    <<<dim3(16, 8, BATCH), 256, 0, stream>>>(Wof, Ob, out);
}

// Round 15
// 170.414 us; speedup vs baseline: 1.2568x; 1.0204x over previous
//
#include <hip/hip_runtime.h>
#include <math.h>

#define BATCH 8
#define DIMD  512
#define NTOK  1024
#define NH    8
#define CQKV  640
#define DOUT  512

typedef __attribute__((ext_vector_type(8))) short short8;
typedef __attribute__((ext_vector_type(4))) short short4v;
typedef __attribute__((ext_vector_type(4))) float f32x4;

__device__ __forceinline__ short bf16rn(float x) {
    unsigned u = __float_as_uint(x);
    u += 0x7FFF + ((u >> 16) & 1);
    return (short)(u >> 16);
}
__device__ __forceinline__ float bf16tof(short s) {
    return __uint_as_float(((unsigned)(unsigned short)s) << 16);
}
struct HL { short h, l; };
__device__ __forceinline__ HL bf16split(float x) {
    HL r;
    r.h = bf16rn(x);
    r.l = bf16rn(x - bf16tof(r.h));
    return r;
}
__device__ __forceinline__ void dma16(const short* g, short* l) {
    __builtin_amdgcn_global_load_lds(
        (const __attribute__((address_space(1))) unsigned int*)g,
        (__attribute__((address_space(3))) unsigned int*)l, 16, 0, 0);
}
// max over the 16-lane r-group: ds_swizzle xor 1,2,4,8
__device__ __forceinline__ float swzmax16(float v) {
    v = fmaxf(v, __int_as_float(__builtin_amdgcn_ds_swizzle(__float_as_int(v), 0x041F)));
    v = fmaxf(v, __int_as_float(__builtin_amdgcn_ds_swizzle(__float_as_int(v), 0x081F)));
    v = fmaxf(v, __int_as_float(__builtin_amdgcn_ds_swizzle(__float_as_int(v), 0x101F)));
    v = fmaxf(v, __int_as_float(__builtin_amdgcn_ds_swizzle(__float_as_int(v), 0x201F)));
    return v;
}
// pack (truncate) two f32 -> two bf16 in one dword
__device__ __forceinline__ unsigned packbf2(float f0, float f1) {
    return __builtin_amdgcn_perm(__float_as_uint(f1), __float_as_uint(f0), 0x07060302);
}

// Fragment-order conventions (verified end-to-end R2/R4-R13):
//  A-frag: lane=(q,r), element A[m=r][k=q*8+j] per 32-k chunk
//  B-frag: element B[ncol=r][k=q*8+j]
//  C/D   : D[m=q*4+reg][ncol=r]
// K/V frag buffers: [b][t16][ic8][lane64][j8]; Q: [b][h][nt64][kc2][lane64][j8]
// O frag buffer:    [b][nt64][ct16][lane64][j8]

// ---------------------------------------------------------------------------
// prepack_all: fused prepack_x (blocks 0-1023) + prepack_w (1024-1183) +
// prepack_wout (1184-1311).  (unchanged from R13)
// ---------------------------------------------------------------------------
__global__ __launch_bounds__(256) void prepack_all(const float* __restrict__ x,
                                                   const float* __restrict__ qp,
                                                   const float* __restrict__ kp,
                                                   const float* __restrict__ vp,
                                                   const float* __restrict__ wout,
                                                   short* __restrict__ whi,
                                                   short* __restrict__ wlo,
                                                   short* __restrict__ xhi,
                                                   short* __restrict__ xlo,
                                                   short* __restrict__ wof) {
    __shared__ float Cs[64][65];
    const int blk = blockIdx.x;
    const int t = threadIdx.x;
    if (blk < 1024) {
        const int nt = blk & 15, dt = (blk >> 4) & 7, b = blk >> 7;
        #pragma unroll
        for (int i = 0; i < 4; ++i) {
            int row = (t >> 4) + i * 16;
            float4 v = *(const float4*)(x + ((size_t)(b * DIMD + dt * 64 + row)) * NTOK
                                          + nt * 64 + (t & 15) * 4);
            Cs[row][(t & 15) * 4 + 0] = v.x;
            Cs[row][(t & 15) * 4 + 1] = v.y;
            Cs[row][(t & 15) * 4 + 2] = v.z;
            Cs[row][(t & 15) * 4 + 3] = v.w;
        }
        __syncthreads();
        for (int u = t; u < 512; u += 256) {
            int lane2 = u & 63, cidx = u >> 6;
            int q2 = lane2 >> 4, r2 = lane2 & 15;
            int kt_loc = cidx & 1, mt_loc = cidx >> 1;
            short8 h8, l8;
            #pragma unroll
            for (int j = 0; j < 8; ++j) {
                HL s = bf16split(Cs[kt_loc * 32 + q2 * 8 + j][mt_loc * 16 + r2]);
                h8[j] = s.h; l8[j] = s.l;
            }
            size_t off = (((size_t)(b * 64 + nt * 4 + mt_loc)) * 16 + dt * 2 + kt_loc) * 512
                         + lane2 * 8;
            *(short8*)&xhi[off] = h8;
            *(short8*)&xlo[off] = l8;
        }
    } else if (blk < 1184) {
        int tid = (blk - 1024) * 256 + t;
        int lane = tid & 63, kt = (tid >> 6) & 15, ct = tid >> 10;
        int q = lane >> 4, r = lane & 15;
        int c = ct * 16 + r;
        short8 h, l;
        #pragma unroll
        for (int j = 0; j < 8; ++j) {
            int d = kt * 32 + q * 8 + j;
            float v;
            if (c < 64)       v = kp[d * 64 + c];
            else if (c < 128) v = vp[d * 64 + (c - 64)];
            else              v = qp[(size_t)(c - 128) * DIMD + d];
            HL s = bf16split(v);
            h[j] = s.h; l[j] = s.l;
        }
        *(short8*)&whi[(size_t)tid * 8] = h;
        *(short8*)&wlo[(size_t)tid * 8] = l;
    } else {
        int tid = (blk - 1184) * 256 + t;
        int lane = tid & 63, kt = (tid >> 6) & 15, mt = tid >> 10;
        int q = lane >> 4, r = lane & 15;
        const float* src = wout + (size_t)(mt * 16 + r) * DOUT + kt * 32 + q * 8;
        short8 h;
        #pragma unroll
        for (int j = 0; j < 8; ++j) h[j] = bf16rn(src[j]);
        *(short8*)&wof[(size_t)tid * 8] = h;
    }
}

// ---------------------------------------------------------------------------
// qkv_gemm: split-bf16 MFMA + fused frag emission.  BM=128(n) BN=64(c):
// each wave owns 2 row-tiles so every B ds_read_b128 feeds 6 MFMAs.
// Grid 640, XCD swizzle.  LDS: 48 KB staging / Cs[128][65] epilogue alias.
// ---------------------------------------------------------------------------
__global__ __launch_bounds__(256) void qkv_gemm(const short* __restrict__ xhi,
                                                const short* __restrict__ xlo,
                                                const short* __restrict__ whi,
                                                const short* __restrict__ wlo,
                                                short* __restrict__ khi,
                                                short* __restrict__ klo,
                                                short* __restrict__ vf,
                                                short* __restrict__ qhi,
                                                short* __restrict__ qlo) {
    __shared__ __align__(16) char pool[49152];
    short* Ah = (short*)pool;            // 8192 shorts (16 KB)
    short* Al = Ah + 8192;               // 16 KB
    short* Bh = Al + 8192;               // 4096 shorts (8 KB)
    short* Bl = Bh + 4096;               // 8 KB
    float (*Cs)[65] = (float(*)[65])pool;   // 128*65*4 = 33280 B (alias)

    // XCD swizzle: idx = (g&7) + 8*((g>>3)*10 + cb), g = M-tile id [0,64)
    const int idx = blockIdx.x;
    const int low = idx & 7, rest = idx >> 3;
    const int cb = rest % 10, gh = rest / 10;
    const int g = gh * 8 + low;
    const int b = g >> 3, bml = g & 7;      // rows n0 = bml*128

    const int tid = threadIdx.x, w = tid >> 6, lane = tid & 63;
    const int q = lane >> 4, r = lane & 15;
    f32x4 acc[2][4];
    #pragma unroll
    for (int i = 0; i < 2; ++i)
        #pragma unroll
        for (int j = 0; j < 4; ++j) acc[i][j] = (f32x4){0.f, 0.f, 0.f, 0.f};

    for (int it = 0; it < 8; ++it) {
        __syncthreads();
        for (int u = w; u < 16; u += 4) {
            size_t ga = ((size_t)((b * 64 + bml * 8 + (u >> 1)) * 16 + it * 2 + (u & 1))) * 512 + lane * 8;
            dma16(xhi + ga, &Ah[u * 512]);
            dma16(xlo + ga, &Al[u * 512]);
            if (u < 8) {
                size_t gb = ((size_t)((cb * 4 + (u >> 1)) * 16 + it * 2 + (u & 1))) * 512 + lane * 8;
                dma16(whi + gb, &Bh[u * 512]);
                dma16(wlo + gb, &Bl[u * 512]);
            }
        }
        __syncthreads();
        #pragma unroll
        for (int kc = 0; kc < 2; ++kc) {
            short8 ah[2], al[2];
            #pragma unroll
            for (int rt = 0; rt < 2; ++rt) {
                ah[rt] = *(short8*)&Ah[((w * 2 + rt) * 2 + kc) * 512 + lane * 8];
                al[rt] = *(short8*)&Al[((w * 2 + rt) * 2 + kc) * 512 + lane * 8];
            }
            #pragma unroll
            for (int tt = 0; tt < 4; ++tt) {
                short8 bh = *(short8*)&Bh[(tt * 2 + kc) * 512 + lane * 8];
                short8 bl = *(short8*)&Bl[(tt * 2 + kc) * 512 + lane * 8];
                #pragma unroll
                for (int rt = 0; rt < 2; ++rt) {
                    acc[rt][tt] = __builtin_amdgcn_mfma_f32_16x16x32_bf16(ah[rt], bh, acc[rt][tt], 0, 0, 0);
                    acc[rt][tt] = __builtin_amdgcn_mfma_f32_16x16x32_bf16(ah[rt], bl, acc[rt][tt], 0, 0, 0);
                    acc[rt][tt] = __builtin_amdgcn_mfma_f32_16x16x32_bf16(al[rt], bh, acc[rt][tt], 0, 0, 0);
                }
            }
        }
    }

    // ---- fused epilogue: C tile (128x64) -> LDS -> frag-order bf16 global ----
    __syncthreads();
    #pragma unroll
    for (int rt = 0; rt < 2; ++rt)
        #pragma unroll
        for (int reg = 0; reg < 4; ++reg)
            #pragma unroll
            for (int tt = 0; tt < 4; ++tt)
                Cs[w * 32 + rt * 16 + q * 4 + reg][tt * 16 + r] = acc[rt][tt][reg];
    __syncthreads();

    if (cb == 0) {
        // K: 2 t-tiles; elem K[m=t*64+i*16+r2][kd=cc*32+q2*8+j], ic=i*2+cc
        for (int u = tid; u < 1024; u += 256) {
            int lane2 = u & 63, ic = (u >> 6) & 7, tl = u >> 9;
            int q2 = lane2 >> 4, r2 = lane2 & 15;
            int i = ic >> 1, cc = ic & 1;
            short8 h8, l8;
            #pragma unroll
            for (int j = 0; j < 8; ++j) {
                HL s = bf16split(Cs[tl * 64 + i * 16 + r2][cc * 32 + q2 * 8 + j]);
                h8[j] = s.h; l8[j] = s.l;
            }
            size_t off = ((size_t)(b * 16 + bml * 2 + tl) * 8 + ic) * 512 + lane2 * 8;
            *(short8*)&khi[off] = h8;
            *(short8*)&klo[off] = l8;
        }
    } else if (cb == 1) {
        // V: 2 t-tiles; elem V[m=cc*32+q2*8+j][v=tv*16+r2], ic=tv*2+cc
        for (int u = tid; u < 1024; u += 256) {
            int lane2 = u & 63, ic = (u >> 6) & 7, tl = u >> 9;
            int q2 = lane2 >> 4, r2 = lane2 & 15;
            int tv = ic >> 1, cc = ic & 1;
            short8 v8;
            #pragma unroll
            for (int j = 0; j < 8; ++j)
                v8[j] = bf16rn(Cs[tl * 64 + cc * 32 + q2 * 8 + j][tv * 16 + r2]);
            size_t off = ((size_t)(b * 16 + bml * 2 + tl) * 8 + ic) * 512 + lane2 * 8;
            *(short8*)&vf[off] = v8;
        }
    } else {
        // Q head hd: 8 nt-tiles x 2 kc = 16 chunks -> u < 1024 (R14 bug: was 2048)
        const int hd = cb - 2;
        const float qscale = 0.125f * 1.44269504f;
        for (int u = tid; u < 1024; u += 256) {
            int lane2 = u & 63, ch = u >> 6;        // ch in [0,16)
            int q2 = lane2 >> 4, r2 = lane2 & 15;
            int kc = ch & 1, ntl = ch >> 1;         // ntl in [0,8)
            short8 h8, l8;
            #pragma unroll
            for (int j = 0; j < 8; ++j) {
                HL s = bf16split(Cs[ntl * 16 + r2][kc * 32 + q2 * 8 + j] * qscale);
                h8[j] = s.h; l8[j] = s.l;
            }
            size_t off = ((((size_t)(b * 8 + hd) * 64 + bml * 8 + ntl) * 2 + kc) * 64 + lane2) * 8;
            *(short8*)&qhi[off] = h8;
            *(short8*)&qlo[off] = l8;
        }
    }
}

// ---------------------------------------------------------------------------
// attn: MFMA flash attention (unchanged from R13: XCD map, lazy softmax,
// swizzle-max, perm-pack; proven 72.5 µs plateau).
// ---------------------------------------------------------------------------
__global__ __launch_bounds__(256) void attn_mfma(const short* __restrict__ qhi_g,
                                                 const short* __restrict__ qlo_g,
                                                 const short* __restrict__ khi_g,
                                                 const short* __restrict__ klo_g,
                                                 const short* __restrict__ vf_g,
                                                 short* __restrict__ ob) {
    __shared__ short Khi[4096], Klo[4096], Vf[4096];
    __shared__ short Pbuf[4 * 64 * 36];
    const int blk = blockIdx.x;
    const int b   = blk & 7;
    const int h   = (blk >> 3) & 7;
    const int qt  = blk >> 6;
    const int tid = threadIdx.x;
    const int w    = tid >> 6;
    const int lane = tid & 63;
    const int q    = lane >> 4;
    const int r    = lane & 15;
    short* Pw = Pbuf + w * (64 * 36);

    short8 qhi[2][2], qlo[2][2];
    #pragma unroll
    for (int rt = 0; rt < 2; ++rt) {
        const int nt = qt * 8 + w * 2 + rt;
        #pragma unroll
        for (int c = 0; c < 2; ++c) {
            size_t off = ((((size_t)(b * 8 + h) * 64 + nt) * 2 + c) * 64 + lane) * 8;
            qhi[rt][c] = *(const short8*)&qhi_g[off];
            qlo[rt][c] = *(const short8*)&qlo_g[off];
        }
    }

    short8 bones;
    #pragma unroll
    for (int j = 0; j < 8; ++j) bones[j] = (short)0x3F80;

    f32x4 oacc[2][4], lacc[2];
    float m_[2][4];
    #pragma unroll
    for (int rt = 0; rt < 2; ++rt) {
        #pragma unroll
        for (int tt = 0; tt < 4; ++tt) oacc[rt][tt] = (f32x4){0.f, 0.f, 0.f, 0.f};
        lacc[rt] = (f32x4){0.f, 0.f, 0.f, 0.f};
        #pragma unroll
        for (int i = 0; i < 4; ++i) m_[rt][i] = -1e30f;
    }

    for (int t = 0; t < 16; ++t) {
        __syncthreads();
        const size_t kb = ((size_t)(b * 16 + t) * 8) * 512;
        for (int ch = w; ch < 8; ch += 4) {
            dma16(khi_g + kb + ch * 512 + lane * 8, &Khi[ch * 512]);
            dma16(klo_g + kb + ch * 512 + lane * 8, &Klo[ch * 512]);
            dma16(vf_g  + kb + ch * 512 + lane * 8, &Vf [ch * 512]);
        }
        __syncthreads();

        f32x4 s[2][4];
        #pragma unroll
        for (int rt = 0; rt < 2; ++rt)
            #pragma unroll
            for (int tt = 0; tt < 4; ++tt) s[rt][tt] = (f32x4){0.f, 0.f, 0.f, 0.f};
        #pragma unroll
        for (int c = 0; c < 2; ++c) {
            #pragma unroll
            for (int tt = 0; tt < 4; ++tt) {
                short8 kh = *(short8*)&Khi[((tt * 2 + c) * 64 + lane) * 8];
                short8 kl = *(short8*)&Klo[((tt * 2 + c) * 64 + lane) * 8];
                #pragma unroll
                for (int rt = 0; rt < 2; ++rt) {
                    s[rt][tt] = __builtin_amdgcn_mfma_f32_16x16x32_bf16(qhi[rt][c], kh, s[rt][tt], 0, 0, 0);
                    s[rt][tt] = __builtin_amdgcn_mfma_f32_16x16x32_bf16(qhi[rt][c], kl, s[rt][tt], 0, 0, 0);
                    s[rt][tt] = __builtin_amdgcn_mfma_f32_16x16x32_bf16(qlo[rt][c], kh, s[rt][tt], 0, 0, 0);
                }
            }
        }

        // lazy online softmax (log2 space)
        float pmax[2][4];
        bool need = false;
        #pragma unroll
        for (int rt = 0; rt < 2; ++rt)
            #pragma unroll
            for (int reg = 0; reg < 4; ++reg) {
                float pm = fmaxf(fmaxf(s[rt][0][reg], s[rt][1][reg]),
                                 fmaxf(s[rt][2][reg], s[rt][3][reg]));
                pmax[rt][reg] = pm;
                need = need || (pm > m_[rt][reg] + 30.f);
            }
        if (__any((int)need)) {
            #pragma unroll
            for (int rt = 0; rt < 2; ++rt)
                #pragma unroll
                for (int reg = 0; reg < 4; ++reg) {
                    float smax = swzmax16(pmax[rt][reg]);
                    float nm    = fmaxf(m_[rt][reg], smax);
                    float alpha = exp2f(m_[rt][reg] - nm);
                    m_[rt][reg] = nm;
                    lacc[rt][reg] *= alpha;
                    #pragma unroll
                    for (int tt = 0; tt < 4; ++tt) oacc[rt][tt][reg] *= alpha;
                }
        }
        #pragma unroll
        for (int rt = 0; rt < 2; ++rt)
            #pragma unroll
            for (int reg = 0; reg < 4; ++reg)
                #pragma unroll
                for (int tt = 0; tt < 4; ++tt)
                    s[rt][tt][reg] = exp2f(s[rt][tt][reg] - m_[rt][reg]);

        #pragma unroll
        for (int rt = 0; rt < 2; ++rt) {
            #pragma unroll
            for (int tt = 0; tt < 4; ++tt) {
                uint2 pk;
                pk.x = packbf2(s[rt][tt][0], s[rt][tt][1]);
                pk.y = packbf2(s[rt][tt][2], s[rt][tt][3]);
                *(uint2*)&Pw[(r + 16 * tt) * 36 + rt * 16 + q * 4] = pk;
            }
        }

        #pragma unroll
        for (int c = 0; c < 2; ++c) {
            short8 pf[2];
            #pragma unroll
            for (int rt = 0; rt < 2; ++rt)
                #pragma unroll
                for (int j = 0; j < 8; ++j)
                    pf[rt][j] = Pw[(c * 32 + q * 8 + j) * 36 + rt * 16 + r];
            #pragma unroll
            for (int rt = 0; rt < 2; ++rt)
                lacc[rt] = __builtin_amdgcn_mfma_f32_16x16x32_bf16(pf[rt], bones, lacc[rt], 0, 0, 0);
            #pragma unroll
            for (int tt = 0; tt < 4; ++tt) {
                short8 vfr = *(short8*)&Vf[((tt * 2 + c) * 64 + lane) * 8];
                #pragma unroll
                for (int rt = 0; rt < 2; ++rt)
                    oacc[rt][tt] = __builtin_amdgcn_mfma_f32_16x16x32_bf16(pf[rt], vfr, oacc[rt][tt], 0, 0, 0);
            }
        }
    }

    #pragma unroll
    for (int rt = 0; rt < 2; ++rt) {
        const int nt = qt * 8 + w * 2 + rt;
        #pragma unroll
        for (int reg = 0; reg < 4; ++reg) {
            float inv = 1.f / lacc[rt][reg];
            #pragma unroll
            for (int tt = 0; tt < 4; ++tt) {
                int ct = h * 2 + (tt >> 1);
                int lanep = ((tt & 1) * 2 + (r >> 3)) * 16 + q * 4 + reg;
                ob[((((size_t)b * 64 + nt) * 16 + ct) * 64 + lanep) * 8 + (r & 7)] =
                    bf16rn(oacc[rt][tt][reg] * inv);
            }
        }
    }
}

// ---------------------------------------------------------------------------
// out_gemm: plain bf16 MFMA, double-buffered staging (unchanged).
// ---------------------------------------------------------------------------
__global__ __launch_bounds__(256) void out_gemm(const short* __restrict__ wof,
                                                const short* __restrict__ obf,
                                                float* __restrict__ out) {
    __shared__ short Ah[2][4096];
    __shared__ short Bh[2][4096];
    const int b = blockIdx.z, bd = blockIdx.y, bn = blockIdx.x;
    const int tid = threadIdx.x, w = tid >> 6, lane = tid & 63;
    const int q = lane >> 4, r = lane & 15;
    f32x4 acc[4];
    #pragma unroll
    for (int j = 0; j < 4; ++j) acc[j] = (f32x4){0.f, 0.f, 0.f, 0.f};

    for (int u = w; u < 8; u += 4) {
        size_t ga = ((size_t)((bd * 4 + (u >> 1)) * 16 + (u & 1))) * 512 + lane * 8;
        dma16(wof + ga, &Ah[0][u * 512]);
        size_t gb = ((size_t)((b * 64 + bn * 4 + (u >> 1)) * 16 + (u & 1))) * 512 + lane * 8;
        dma16(obf + gb, &Bh[0][u * 512]);
    }

    for (int it = 0; it < 8; ++it) {
        const int cur = it & 1;
        __syncthreads();
        if (it < 7) {
            for (int u = w; u < 8; u += 4) {
                size_t ga = ((size_t)((bd * 4 + (u >> 1)) * 16 + (it + 1) * 2 + (u & 1))) * 512 + lane * 8;
                dma16(wof + ga, &Ah[cur ^ 1][u * 512]);
                size_t gb = ((size_t)((b * 64 + bn * 4 + (u >> 1)) * 16 + (it + 1) * 2 + (u & 1))) * 512 + lane * 8;
                dma16(obf + gb, &Bh[cur ^ 1][u * 512]);
            }
        }
        #pragma unroll
        for (int kc = 0; kc < 2; ++kc) {
            short8 a = *(short8*)&Ah[cur][(w * 2 + kc) * 512 + lane * 8];
            #pragma unroll
            for (int tt = 0; tt < 4; ++tt) {
                short8 bb = *(short8*)&Bh[cur][(tt * 2 + kc) * 512 + lane * 8];
                acc[tt] = __builtin_amdgcn_mfma_f32_16x16x32_bf16(a, bb, acc[tt], 0, 0, 0);
            }
        }
    }
    const int d_base = bd * 64 + w * 16;
    #pragma unroll
    for (int reg = 0; reg < 4; ++reg)
        #pragma unroll
        for (int tt = 0; tt < 4; ++tt)
            out[((size_t)b * DOUT + d_base + q * 4 + reg) * NTOK
                + bn * 64 + tt * 16 + r] = acc[tt][reg];
}

// ---------------------------------------------------------------------------
extern "C" void kernel_launch(void* const* d_in, const int* in_sizes, int n_in,
                              void* d_out, int out_size, void* d_ws, size_t ws_size,
                              hipStream_t stream) {
    const float* x  = (const float*)d_in[0];
    const float* qp = (const float*)d_in[1];
    const float* kp = (const float*)d_in[2];
    const float* vp = (const float*)d_in[3];
    const float* op = (const float*)d_in[4];
    float* out = (float*)d_out;

    // workspace: 38.5 MB (proven R12/R13)
    short* Whi = (short*)d_ws;                 // 327,680
    short* Wlo = Whi + 327680;                 // 327,680
    short* Xhi = Wlo + 327680;                 // 4,194,304
    short* Xlo = Xhi + 4194304;                // 4,194,304
    short* Qhi = Xlo + 4194304;                // 4,194,304
    short* Qlo = Qhi + 4194304;                // 4,194,304
    short* Khi = Qlo + 4194304;                // 524,288
    short* Klo = Khi + 524288;                 // 524,288
    short* Vf  = Klo + 524288;                 // 524,288
    short* Wof = Vf  + 524288;                 // 262,144
    short* Ob  = Xhi;                          // alias: X dead after qkv_gemm

    prepack_all <<<1312, 256, 0, stream>>>(x, qp, kp, vp, op,
                                           Whi, Wlo, Xhi, Xlo, Wof);
    qkv_gemm    <<<640, 256, 0, stream>>>(Xhi, Xlo, Whi, Wlo,
                                          Khi, Klo, Vf, Qhi, Qlo);
    attn_mfma   <<<512, 256, 0, stream>>>(Qhi, Qlo, Khi, Klo, Vf, Ob);
    out_gemm    <<<dim3(16, 8, BATCH), 256, 0, stream>>>(Wof, Ob, out);
}